// Round 11
// baseline (523.159 us; speedup 1.0000x reference)
//
#include <hip/hip_runtime.h>
#include <math.h>

static constexpr int E = 256;   // embed/seq/chn dim (all equal)
static constexpr int BTOT = 256;

typedef __bf16 bf16;
typedef __bf16 bf16x8 __attribute__((ext_vector_type(8)));
typedef __bf16 bf16x4 __attribute__((ext_vector_type(4)));
typedef float f32x4 __attribute__((ext_vector_type(4)));

// async global->LDS, 16B per lane. LDS dest is wave-uniform base + lane*16.
__device__ __forceinline__ void gload16(const void* g, void* l) {
  __builtin_amdgcn_global_load_lds(
      (const __attribute__((address_space(1))) void*)g,
      (__attribute__((address_space(3))) void*)l, 16, 0, 0);
}

// XCD-aware flat-grid decode (bijective iff nPanels%8==0, else identity).
__device__ __forceinline__ void xcd_decode(int b, int NX, int nPanels, int& x, int& g) {
  if ((nPanels & 7) == 0) {
    int gLo = b & 7;
    int t2 = b >> 3;
    x = t2 % NX;
    g = (t2 / NX) * 8 + gLo;
  } else {
    x = b % NX;
    g = b / NX;
  }
}

__device__ __forceinline__ float fsig(float x) {
  return __fdividef(1.0f, 1.0f + __expf(-x));
}

// ---------------- prep: weight transpose f32[R][C] -> bf16[C][R] ----------------
__global__ __launch_bounds__(256) void k_wT(const float* __restrict__ src,
                                            bf16* __restrict__ dst, int R, int C) {
  __shared__ float lds[32][33];
  int tiles_c = C >> 5;
  int tc = blockIdx.x % tiles_c;
  int tr = blockIdx.x / tiles_c;
  int r0 = tr << 5, c0 = tc << 5;
  int t = threadIdx.x, cc = t & 31, rr0 = t >> 5;
#pragma unroll
  for (int p = 0; p < 4; ++p) {
    int rr = rr0 + p * 8;
    lds[rr][cc] = src[(size_t)(r0 + rr) * C + (c0 + cc)];
  }
  __syncthreads();
#pragma unroll
  for (int p = 0; p < 4; ++p) {
    int rr = rr0 + p * 8;
    dst[(size_t)(c0 + rr) * R + (r0 + cc)] = (bf16)lds[cc][rr];
  }
}

// ---------------- prep: lambda scalar ----------------
__global__ void k_lam(const float* lq1, const float* lk1, const float* lq2,
                      const float* lk2, float lambda_init, float* lamOut) {
  int t = threadIdx.x;
  float v1 = lq1[t] * lk1[t];
  float v2 = lq2[t] * lk2[t];
  __shared__ float s1[4], s2[4];
#pragma unroll
  for (int o = 32; o; o >>= 1) { v1 += __shfl_xor(v1, o); v2 += __shfl_xor(v2, o); }
  if ((t & 63) == 0) { s1[t >> 6] = v1; s2[t >> 6] = v2; }
  __syncthreads();
  if (t == 0) {
    float a = s1[0] + s1[1] + s1[2] + s1[3];
    float b = s2[0] + s2[1] + s2[2] + s2[3];
    *lamOut = expf(a) - expf(b) + lambda_init;
  }
}

// ---------------- per-column (axis-i) RMS of x: rinvA[b][j] ----------------
__global__ __launch_bounds__(1024) void k_rmsA(const float* __restrict__ x, int batchBase,
                                               float* __restrict__ rinvA) {
  __shared__ float red[4][257];
  int lz = blockIdx.x;
  int g = batchBase + lz;
  int t = threadIdx.x, j = t & 255, qd = t >> 8;
  const float* xb = x + (size_t)g * E * E;
  float s = 0.f;
#pragma unroll 4
  for (int ii = 0; ii < 64; ++ii) {
    float v = xb[(size_t)(qd * 64 + ii) * E + j];
    s += v * v;
  }
  red[qd][j] = s;
  __syncthreads();
  if (qd == 0) {
    float tot = red[0][j] + red[1][j] + red[2][j] + red[3][j];
    rinvA[lz * E + j] = __fdividef(1.0f, sqrtf(tot) * 0.0625f + 1e-8f);
  }
}

// ---------------- fused: transpose + rmsnorm-scale + trend/seasonal ----------------
__global__ __launch_bounds__(256) void k_prep(const float* __restrict__ x, int batchBase,
                                              const float* __restrict__ rinvA,
                                              const float* __restrict__ lnattn,
                                              bf16* __restrict__ a_t,
                                              bf16* __restrict__ tr_t, bf16* __restrict__ se_t) {
  __shared__ float lA[36][261];
  int lz = blockIdx.y, g = batchBase + lz;
  int i0 = blockIdx.x << 5;
  int t = threadIdx.x;
  const float* xb = x + (size_t)g * E * E;
  float rj = rinvA[lz * E + t];
#pragma unroll
  for (int rr = 0; rr < 36; ++rr) {
    int gi = i0 - 2 + rr;
    gi = gi < 0 ? 0 : (gi > 255 ? 255 : gi);
    float v = xb[(size_t)gi * E + t];
    lA[rr][t] = lnattn[gi] * v * rj;
  }
  __syncthreads();
  size_t bo = (size_t)lz * E * E;
  int ic = t & 31, jg = t >> 5;
#pragma unroll 4
  for (int jj = 0; jj < 32; ++jj) {
    int j = jg + jj * 8;
    float a0 = lA[ic][j], a1 = lA[ic + 1][j], a2 = lA[ic + 2][j];
    float a3 = lA[ic + 3][j], a4 = lA[ic + 4][j];
    float tr = (a0 + a1 + a2 + a3 + a4) * 0.2f;
    size_t o = bo + (size_t)j * E + i0 + ic;
    a_t[o] = (bf16)a2;
    tr_t[o] = (bf16)tr;
    se_t[o] = (bf16)(a2 - tr);
  }
}

// ---------------- merged q & k projection GEMMs (one dispatch) --------------------
__global__ __launch_bounds__(256) void gemm_qk(
    const bf16* __restrict__ A1, const bf16* __restrict__ A2,
    const bf16* __restrict__ B1, const bf16* __restrict__ B2,
    bf16* __restrict__ O1, bf16* __restrict__ O2,
    const float* __restrict__ bias1, const float* __restrict__ bias2, int cnt) {
  __shared__ __align__(128) bf16 As[128][64];
  __shared__ __align__(128) bf16 Bs[128][64];
  int xdec, gdec;
  xcd_decode(blockIdx.x, 4, 4 * cnt, xdec, gdec);
  int lz = gdec >> 2;
  int sel = (gdec >> 1) & 1;
  int mb = (gdec & 1) << 7, nb = xdec << 7;
  const bf16* Ab = (sel ? A2 : A1) + (size_t)lz * 65536;
  const bf16* Bb = sel ? B2 : B1;
  bf16* Out = (sel ? O2 : O1) + (size_t)lz * 131072;
  const float* biasN = sel ? bias2 : bias1;
  int t = threadIdx.x, lane = t & 63, wv = t >> 6;
  int wr = wv >> 1, wc = wv & 1;
  int lrow = lane >> 3;
  int kel = ((lane & 7) ^ lrow) << 3;
  f32x4 acc[4][4];
  const f32x4 z4 = {0.f, 0.f, 0.f, 0.f};
#pragma unroll
  for (int a = 0; a < 4; ++a)
#pragma unroll
    for (int b = 0; b < 4; ++b) acc[a][b] = z4;
  for (int k0 = 0; k0 < 256; k0 += 64) {
    __syncthreads();
#pragma unroll
    for (int i = 0; i < 4; ++i) {
      int rb = i * 32 + wv * 8;
      gload16(&Ab[(size_t)(mb + rb + lrow) * 256 + k0 + kel], &As[rb][0]);
      gload16(&Bb[(size_t)(nb + rb + lrow) * 256 + k0 + kel], &Bs[rb][0]);
    }
    __syncthreads();
    __builtin_amdgcn_s_setprio(1);
#pragma unroll
    for (int kk = 0; kk < 2; ++kk) {
      int kb = (kk * 64 + ((lane >> 4) << 4)) ^ ((lane & 7) << 4);
      bf16x8 af[4], bfr[4];
#pragma unroll
      for (int mi = 0; mi < 4; ++mi)
        af[mi] = *(const bf16x8*)((const char*)As + (wr * 64 + mi * 16 + (lane & 15)) * 128 + kb);
#pragma unroll
      for (int ni = 0; ni < 4; ++ni)
        bfr[ni] = *(const bf16x8*)((const char*)Bs + (wc * 64 + ni * 16 + (lane & 15)) * 128 + kb);
#pragma unroll
      for (int mi = 0; mi < 4; ++mi)
#pragma unroll
        for (int ni = 0; ni < 4; ++ni)
          acc[mi][ni] = __builtin_amdgcn_mfma_f32_16x16x32_bf16(af[mi], bfr[ni],
                                                                acc[mi][ni], 0, 0, 0);
    }
    __builtin_amdgcn_s_setprio(0);
  }
  int colB = nb + wc * 64 + (lane & 15);
  int rowB = mb + wr * 64 + ((lane >> 4) << 2);
#pragma unroll
  for (int mi = 0; mi < 4; ++mi) {
#pragma unroll
    for (int ni = 0; ni < 4; ++ni) {
      int col = colB + ni * 16;
      float bN = biasN[col];
#pragma unroll
      for (int r = 0; r < 4; ++r) {
        int row = rowB + mi * 16 + r;
        Out[(size_t)row * 512 + col] = (bf16)(acc[mi][ni][r] + bN);
      }
    }
  }
}

// ---------------- BT GEMM (used for v projection): EPI=2 bf16 out + biasM ---------
template <int EPI>
__global__ __launch_bounds__(256) void gemm_bt(
    const bf16* __restrict__ A, int lda, size_t aStride,
    const bf16* __restrict__ B, int ldb, size_t bStride,
    bf16* __restrict__ Out, int ldo, size_t oStride, int K,
    const float* __restrict__ biasN, const float* __restrict__ biasM,
    int NX, int NY, int nPanels) {
  __shared__ __align__(128) bf16 As[128][64];
  __shared__ __align__(128) bf16 Bs[128][64];
  int xdec, gdec;
  xcd_decode(blockIdx.x, NX, nPanels, xdec, gdec);
  int lz = gdec / NY;
  int mb = (gdec % NY) << 7, nb = xdec << 7;
  const bf16* Ab = A + (size_t)lz * aStride;
  const bf16* Bb = B + (size_t)lz * bStride;
  int t = threadIdx.x, lane = t & 63, wv = t >> 6;
  int wr = wv >> 1, wc = wv & 1;
  int lrow = lane >> 3;
  int kel = ((lane & 7) ^ lrow) << 3;
  f32x4 acc[4][4];
  const f32x4 z4 = {0.f, 0.f, 0.f, 0.f};
#pragma unroll
  for (int a = 0; a < 4; ++a)
#pragma unroll
    for (int b = 0; b < 4; ++b) acc[a][b] = z4;
  for (int k0 = 0; k0 < K; k0 += 64) {
    __syncthreads();
#pragma unroll
    for (int i = 0; i < 4; ++i) {
      int rb = i * 32 + wv * 8;
      gload16(&Ab[(size_t)(mb + rb + lrow) * lda + k0 + kel], &As[rb][0]);
      gload16(&Bb[(size_t)(nb + rb + lrow) * ldb + k0 + kel], &Bs[rb][0]);
    }
    __syncthreads();
    __builtin_amdgcn_s_setprio(1);
#pragma unroll
    for (int kk = 0; kk < 2; ++kk) {
      int kb = (kk * 64 + ((lane >> 4) << 4)) ^ ((lane & 7) << 4);
      bf16x8 af[4], bfr[4];
#pragma unroll
      for (int mi = 0; mi < 4; ++mi)
        af[mi] = *(const bf16x8*)((const char*)As + (wr * 64 + mi * 16 + (lane & 15)) * 128 + kb);
#pragma unroll
      for (int ni = 0; ni < 4; ++ni)
        bfr[ni] = *(const bf16x8*)((const char*)Bs + (wc * 64 + ni * 16 + (lane & 15)) * 128 + kb);
#pragma unroll
      for (int mi = 0; mi < 4; ++mi)
#pragma unroll
        for (int ni = 0; ni < 4; ++ni)
          acc[mi][ni] = __builtin_amdgcn_mfma_f32_16x16x32_bf16(af[mi], bfr[ni],
                                                                acc[mi][ni], 0, 0, 0);
    }
    __builtin_amdgcn_s_setprio(0);
  }
  int colB = nb + wc * 64 + (lane & 15);
  int rowB = mb + wr * 64 + ((lane >> 4) << 2);
#pragma unroll
  for (int mi = 0; mi < 4; ++mi) {
#pragma unroll
    for (int ni = 0; ni < 4; ++ni) {
      int col = colB + ni * 16;
      float bN = 0.f;
      if constexpr (EPI == 1) bN = biasN[col];
#pragma unroll
      for (int r = 0; r < 4; ++r) {
        int row = rowB + mi * 16 + r;
        float v = acc[mi][ni][r];
        if constexpr (EPI == 1) {
          Out[(size_t)lz * oStride + (size_t)row * ldo + col] = (bf16)(v + bN);
        } else {
          Out[(size_t)lz * oStride + (size_t)row * ldo + col] = (bf16)(v + biasM[row]);
        }
      }
    }
  }
}

// ---------------- fused dual score GEMM + dual softmax + diff -> d (bf16) ----------
__global__ __launch_bounds__(512) void k_score(const bf16* __restrict__ q,
                                               const bf16* __restrict__ km,
                                               const float* __restrict__ lamPtr,
                                               bf16* __restrict__ D, int nPanels) {
  __shared__ __align__(128) bf16 As[128][64];
  __shared__ __align__(128) bf16 Bs[256][64];
  __shared__ float red[4][128];
  int xdec, lz;
  xcd_decode(blockIdx.x, 2, nPanels, xdec, lz);
  int mb = xdec << 7;
  const bf16* qb = q + (size_t)lz * E * 512;
  const bf16* kb = km + (size_t)lz * E * 512;
  int t = threadIdx.x, lane = t & 63, wv = t >> 6;
  int wr = wv >> 2, wc = wv & 3;
  int lrow = lane >> 3;
  int kel = ((lane & 7) ^ lrow) << 3;
  f32x4 acc1[4][4], acc2[4][4];
  const f32x4 z4 = {0.f, 0.f, 0.f, 0.f};
#pragma unroll
  for (int a = 0; a < 4; ++a)
#pragma unroll
    for (int b = 0; b < 4; ++b) { acc1[a][b] = z4; acc2[a][b] = z4; }
#pragma unroll
  for (int mat = 0; mat < 2; ++mat) {
    f32x4(*acc)[4] = mat == 0 ? acc1 : acc2;
    const bf16* qm = qb + mat * 256;
    const bf16* kmm = kb + mat * 256;
    for (int k0 = 0; k0 < 256; k0 += 64) {
      __syncthreads();
#pragma unroll
      for (int i = 0; i < 2; ++i) {
        int rb = i * 64 + wv * 8;
        gload16(&qm[(size_t)(mb + rb + lrow) * 512 + k0 + kel], &As[rb][0]);
      }
#pragma unroll
      for (int i = 0; i < 4; ++i) {
        int rb = i * 64 + wv * 8;
        gload16(&kmm[(size_t)(rb + lrow) * 512 + k0 + kel], &Bs[rb][0]);
      }
      __syncthreads();
      __builtin_amdgcn_s_setprio(1);
#pragma unroll
      for (int kk = 0; kk < 2; ++kk) {
        int kb2 = (kk * 64 + ((lane >> 4) << 4)) ^ ((lane & 7) << 4);
        bf16x8 af[4], bfr[4];
#pragma unroll
        for (int mi = 0; mi < 4; ++mi)
          af[mi] = *(const bf16x8*)((const char*)As + (wr * 64 + mi * 16 + (lane & 15)) * 128 + kb2);
#pragma unroll
        for (int ni = 0; ni < 4; ++ni)
          bfr[ni] = *(const bf16x8*)((const char*)Bs + (wc * 64 + ni * 16 + (lane & 15)) * 128 + kb2);
#pragma unroll
        for (int mi = 0; mi < 4; ++mi)
#pragma unroll
          for (int ni = 0; ni < 4; ++ni)
            acc[mi][ni] = __builtin_amdgcn_mfma_f32_16x16x32_bf16(af[mi], bfr[ni],
                                                                  acc[mi][ni], 0, 0, 0);
      }
      __builtin_amdgcn_s_setprio(0);
    }
  }
  float lam = *lamPtr;
  int rbase = wr * 64 + ((lane >> 4) << 2);
  float inv1[4][4], inv2[4][4];
  __syncthreads();
#pragma unroll
  for (int mat = 0; mat < 2; ++mat) {
    f32x4(*acc)[4] = mat == 0 ? acc1 : acc2;
    float(*inv)[4] = mat == 0 ? inv1 : inv2;
    float tmp[4][4];
#pragma unroll
    for (int mi = 0; mi < 4; ++mi)
#pragma unroll
      for (int r = 0; r < 4; ++r) {
        float m = fmaxf(fmaxf(acc[mi][0][r], acc[mi][1][r]),
                        fmaxf(acc[mi][2][r], acc[mi][3][r]));
        m = fmaxf(m, __shfl_xor(m, 1));
        m = fmaxf(m, __shfl_xor(m, 2));
        m = fmaxf(m, __shfl_xor(m, 4));
        m = fmaxf(m, __shfl_xor(m, 8));
        tmp[mi][r] = m;
      }
    if ((lane & 15) == 0) {
#pragma unroll
      for (int mi = 0; mi < 4; ++mi)
#pragma unroll
        for (int r = 0; r < 4; ++r) red[wc][rbase + mi * 16 + r] = tmp[mi][r];
    }
    __syncthreads();
#pragma unroll
    for (int mi = 0; mi < 4; ++mi)
#pragma unroll
      for (int r = 0; r < 4; ++r) {
        int rw = rbase + mi * 16 + r;
        tmp[mi][r] = fmaxf(fmaxf(red[0][rw], red[1][rw]), fmaxf(red[2][rw], red[3][rw]));
      }
    __syncthreads();
#pragma unroll
    for (int mi = 0; mi < 4; ++mi)
#pragma unroll
      for (int r = 0; r < 4; ++r) {
        float m = tmp[mi][r], s = 0.f;
#pragma unroll
        for (int ni = 0; ni < 4; ++ni) {
          float p = __expf(0.25f * (acc[mi][ni][r] - m));
          acc[mi][ni][r] = p;
          s += p;
        }
        s += __shfl_xor(s, 1);
        s += __shfl_xor(s, 2);
        s += __shfl_xor(s, 4);
        s += __shfl_xor(s, 8);
        tmp[mi][r] = s;
      }
    if ((lane & 15) == 0) {
#pragma unroll
      for (int mi = 0; mi < 4; ++mi)
#pragma unroll
        for (int r = 0; r < 4; ++r) red[wc][rbase + mi * 16 + r] = tmp[mi][r];
    }
    __syncthreads();
#pragma unroll
    for (int mi = 0; mi < 4; ++mi)
#pragma unroll
      for (int r = 0; r < 4; ++r) {
        int rw = rbase + mi * 16 + r;
        inv[mi][r] = __fdividef(1.0f, red[0][rw] + red[1][rw] + red[2][rw] + red[3][rw]);
      }
    __syncthreads();
  }
  size_t Dbase = (size_t)lz * E * E;
#pragma unroll
  for (int mi = 0; mi < 4; ++mi)
#pragma unroll
    for (int ni = 0; ni < 4; ++ni) {
      int col = wc * 64 + ni * 16 + (lane & 15);
#pragma unroll
      for (int r = 0; r < 4; ++r) {
        int row = mb + rbase + mi * 16 + r;
        D[Dbase + (size_t)row * E + col] =
            (bf16)(acc1[mi][ni][r] * inv1[mi][r] - lam * acc2[mi][ni][r] * inv2[mi][r]);
      }
    }
}

// ---------------- fused pre = d@v GEMM + row-rmsnorm + residual(x) -> Y (bf16) -----
__global__ __launch_bounds__(512) void k_pv(const bf16* __restrict__ Dm,
                                            const bf16* __restrict__ vT,
                                            const float* __restrict__ x, int batchBase,
                                            const float* __restrict__ nscale,
                                            float oml, bf16* __restrict__ Y, int nPanels) {
  __shared__ __align__(128) bf16 As[128][64];
  __shared__ __align__(128) bf16 Bs[256][64];
  __shared__ float red[4][128];
  int xdec, lz;
  xcd_decode(blockIdx.x, 2, nPanels, xdec, lz);
  int mb = xdec << 7;
  const bf16* Ab = Dm + (size_t)lz * E * E;
  const bf16* Bb = vT + (size_t)lz * E * E;
  int t = threadIdx.x, lane = t & 63, wv = t >> 6;
  int wr = wv >> 2, wc = wv & 3;
  int lrow = lane >> 3;
  int kel = ((lane & 7) ^ lrow) << 3;
  f32x4 acc[4][4];
  const f32x4 z4 = {0.f, 0.f, 0.f, 0.f};
#pragma unroll
  for (int a = 0; a < 4; ++a)
#pragma unroll
    for (int b = 0; b < 4; ++b) acc[a][b] = z4;
  for (int k0 = 0; k0 < 256; k0 += 64) {
    __syncthreads();
#pragma unroll
    for (int i = 0; i < 2; ++i) {
      int rb = i * 64 + wv * 8;
      gload16(&Ab[(size_t)(mb + rb + lrow) * E + k0 + kel], &As[rb][0]);
    }
#pragma unroll
    for (int i = 0; i < 4; ++i) {
      int rb = i * 64 + wv * 8;
      gload16(&Bb[(size_t)(rb + lrow) * E + k0 + kel], &Bs[rb][0]);
    }
    __syncthreads();
    __builtin_amdgcn_s_setprio(1);
#pragma unroll
    for (int kk = 0; kk < 2; ++kk) {
      int kb2 = (kk * 64 + ((lane >> 4) << 4)) ^ ((lane & 7) << 4);
      bf16x8 af[4], bfr[4];
#pragma unroll
      for (int mi = 0; mi < 4; ++mi)
        af[mi] = *(const bf16x8*)((const char*)As + (wr * 64 + mi * 16 + (lane & 15)) * 128 + kb2);
#pragma unroll
      for (int ni = 0; ni < 4; ++ni)
        bfr[ni] = *(const bf16x8*)((const char*)Bs + (wc * 64 + ni * 16 + (lane & 15)) * 128 + kb2);
#pragma unroll
      for (int mi = 0; mi < 4; ++mi)
#pragma unroll
        for (int ni = 0; ni < 4; ++ni)
          acc[mi][ni] = __builtin_amdgcn_mfma_f32_16x16x32_bf16(af[mi], bfr[ni],
                                                                acc[mi][ni], 0, 0, 0);
    }
    __builtin_amdgcn_s_setprio(0);
  }
  int rbase = wr * 64 + ((lane >> 4) << 2);
  float rowinv[4][4];
#pragma unroll
  for (int mi = 0; mi < 4; ++mi)
#pragma unroll
    for (int r = 0; r < 4; ++r) {
      float s = 0.f;
#pragma unroll
      for (int ni = 0; ni < 4; ++ni) {
        float v = acc[mi][ni][r];
        s += v * v;
      }
      s += __shfl_xor(s, 1);
      s += __shfl_xor(s, 2);
      s += __shfl_xor(s, 4);
      s += __shfl_xor(s, 8);
      rowinv[mi][r] = s;
    }
  if ((lane & 15) == 0) {
#pragma unroll
    for (int mi = 0; mi < 4; ++mi)
#pragma unroll
      for (int r = 0; r < 4; ++r) red[wc][rbase + mi * 16 + r] = rowinv[mi][r];
  }
  __syncthreads();
#pragma unroll
  for (int mi = 0; mi < 4; ++mi)
#pragma unroll
    for (int r = 0; r < 4; ++r) {
      int rw = rbase + mi * 16 + r;
      float tot = red[0][rw] + red[1][rw] + red[2][rw] + red[3][rw];
      rowinv[mi][r] = oml * __fdividef(1.0f, sqrtf(tot) * 0.0625f + 1e-8f);
    }
  size_t bo = (size_t)lz * E * E;
  const float* xb = x + (size_t)(batchBase + lz) * E * E;
#pragma unroll
  for (int mi = 0; mi < 4; ++mi)
#pragma unroll
    for (int ni = 0; ni < 4; ++ni) {
      int col = wc * 64 + ni * 16 + (lane & 15);
      float ns = nscale[col];
      int row0 = mb + rbase + mi * 16;
      f32x4 xv = *(const f32x4*)&xb[(size_t)col * E + row0];
#pragma unroll
      for (int r = 0; r < 4; ++r) {
        size_t o = bo + (size_t)(row0 + r) * E + col;
        Y[o] = (bf16)(xv[r] + ns * acc[mi][ni][r] * rowinv[mi][r]);
      }
    }
}

// ---------------- fused column-RMS of Y + scale -> xn (bf16) ----------------------
__global__ __launch_bounds__(256) void k_ffnorm(const bf16* __restrict__ Y,
                                                const float* __restrict__ lnff,
                                                bf16* __restrict__ xn) {
  __shared__ float red[8][33];
  __shared__ float rl[32];
  int lz = blockIdx.y;
  int i0 = blockIdx.x << 5;
  int t = threadIdx.x, ic = t & 31, jg = t >> 5;
  size_t bo = (size_t)lz * E * E;
  float s = 0.f;
#pragma unroll 4
  for (int jj = 0; jj < 32; ++jj) {
    int j = jg + jj * 8;
    float v = (float)Y[bo + (size_t)j * E + i0 + ic];
    s += v * v;
  }
  red[jg][ic] = s;
  __syncthreads();
  if (jg == 0) {
    float tot = 0.f;
#pragma unroll
    for (int g2 = 0; g2 < 8; ++g2) tot += red[g2][ic];
    rl[ic] = __fdividef(1.0f, sqrtf(tot) * 0.0625f + 1e-8f);
  }
  __syncthreads();
  float rinv = rl[ic];
#pragma unroll 4
  for (int jj = 0; jj < 32; ++jj) {
    int j = jg + jj * 8;
    size_t o = bo + (size_t)j * E + i0 + ic;
    xn[o] = (bf16)(lnff[j] * (float)Y[o] * rinv);
  }
}

// ---------------- fused FFN (1024 thr, 128 KB arena, 1-barrier-per-step) ----------
// Change vs round-6: the next-tile stage is issued AFTER the entry barrier, so the
// staging buffer can never alias a straggler's current read -> the trailing barrier
// per k-step is deleted (64 -> 32 barriers/block). vmcnt(0) at entry is exact: the
// only outstanding VMEM ops are the previous step's 2 gload16.
__global__ __launch_bounds__(1024) void k_ffn(const bf16* __restrict__ xn,
                                              const bf16* __restrict__ W1T,
                                              const bf16* __restrict__ W2T,
                                              const float* __restrict__ b1,
                                              const float* __restrict__ b2,
                                              const bf16* __restrict__ Y,
                                              int batchBase, float* __restrict__ out) {
  __shared__ __align__(128) char arena[131072];
  char* Hb = arena;               // 32 KB: H-chunk [64 c][256 e1], eb^(c&7) swizzle
  char* xnL = arena + 32768;      // 32 KB: xn tile as [4 ksub][64 c][64 k]
  char* S0 = arena + 65536;       // 32 KB staging dbuf
  char* S1 = arena + 98304;       // 32 KB
  int bid = blockIdx.x;
  int lz = bid >> 2;
  int c0 = (bid & 3) << 6;
  const bf16* xb = xn + (size_t)lz * E * E + (size_t)c0 * E;
  int t = threadIdx.x, lane = t & 63, wv = t >> 6;
  int lrow = lane >> 3;
  int kel = ((lane & 7) ^ lrow) << 3;
  int l15 = lane & 15, l4 = lane >> 4, l7 = lane & 7;
  int wr1 = wv >> 3, wc1 = wv & 7;   // ph1: 2(M=c64) x 8(N=e1-256)
  int wr2 = wv >> 1, wc2 = wv & 1;   // ph2: 8(M=e2-256) x 2(N=c64)

  float b1v[4][2];
#pragma unroll
  for (int ch = 0; ch < 4; ++ch)
#pragma unroll
    for (int ni = 0; ni < 2; ++ni)
      b1v[ch][ni] = b1[ch * 256 + wc1 * 32 + ni * 16 + l15];

  // prologue: stage xn tile + first W1T k-step into S0
#pragma unroll
  for (int j = 0; j < 2; ++j) {
    int lin = wv * 2 + j;
    int ksub = lin >> 3, rg = (lin & 7) * 8;
    gload16(&xb[(size_t)(rg + lrow) * E + ksub * 64 + kel], xnL + ksub * 8192 + rg * 128);
  }
#pragma unroll
  for (int i = 0; i < 2; ++i) {
    int rb = i * 128 + wv * 8;
    gload16(&W1T[(size_t)(rb + lrow) * 256 + kel], S0 + rb * 128);
  }

  f32x4 acc2[2][2];
  const f32x4 z4 = {0.f, 0.f, 0.f, 0.f};
  acc2[0][0] = z4; acc2[0][1] = z4; acc2[1][0] = z4; acc2[1][1] = z4;
  int cur = 0;

  for (int ch = 0; ch < 4; ++ch) {
    f32x4 acc1[2][2];
    acc1[0][0] = z4; acc1[0][1] = z4; acc1[1][0] = z4; acc1[1][1] = z4;
    // ---- phase 1: H-chunk = silu(xn . W1T[ch]) ----
    for (int k = 0; k < 4; ++k) {
      asm volatile("s_waitcnt vmcnt(0)" ::: "memory");   // current stage landed
      __builtin_amdgcn_s_barrier();                      // all waves see it
      char* Sn = cur ? S0 : S1;
      if (k < 3) {
#pragma unroll
        for (int i = 0; i < 2; ++i) {
          int rb = i * 128 + wv * 8;
          gload16(&W1T[(size_t)(ch * 256 + rb + lrow) * 256 + (k + 1) * 64 + kel], Sn + rb * 128);
        }
      } else {
#pragma unroll
        for (int i = 0; i < 2; ++i) {
          int rb = i * 128 + wv * 8;
          gload16(&W2T[(size_t)(rb + lrow) * 1024 + ch * 256 + kel], Sn + rb * 128);
        }
      }
      char* Sc = cur ? S1 : S0;
#pragma unroll
      for (int kk = 0; kk < 2; ++kk) {
        int kb = (kk * 64 + (l4 << 4)) ^ (l7 << 4);
        bf16x8 af[2], bfr[2];
#pragma unroll
        for (int mi = 0; mi < 2; ++mi)
          af[mi] = *(const bf16x8*)(xnL + k * 8192 + (wr1 * 32 + mi * 16 + l15) * 128 + kb);
#pragma unroll
        for (int ni = 0; ni < 2; ++ni)
          bfr[ni] = *(const bf16x8*)(Sc + (wc1 * 32 + ni * 16 + l15) * 128 + kb);
#pragma unroll
        for (int mi = 0; mi < 2; ++mi)
#pragma unroll
          for (int ni = 0; ni < 2; ++ni)
            acc1[mi][ni] = __builtin_amdgcn_mfma_f32_16x16x32_bf16(af[mi], bfr[ni],
                                                                   acc1[mi][ni], 0, 0, 0);
      }
      cur ^= 1;
    }
    // silu + H write (own writes drained before next barrier)
#pragma unroll
    for (int mi = 0; mi < 2; ++mi)
#pragma unroll
      for (int ni = 0; ni < 2; ++ni) {
        int e1 = wc1 * 32 + ni * 16 + l15;
        float bN = b1v[ch][ni];
#pragma unroll
        for (int r = 0; r < 4; ++r) {
          int c = wr1 * 32 + mi * 16 + l4 * 4 + r;
          float u = acc1[mi][ni][r] + bN;
          float h = u * fsig(u);
          int bo2 = c * 512 + ((((e1 >> 3) ^ (c & 7)) << 4) | ((e1 & 7) * 2));
          *(bf16*)(Hb + bo2) = (bf16)h;
        }
      }
    asm volatile("s_waitcnt lgkmcnt(0)" ::: "memory");
    // ---- phase 2: acc2 += W2T[:, ch-chunk] . H-chunk ----
    for (int k = 0; k < 4; ++k) {
      asm volatile("s_waitcnt vmcnt(0)" ::: "memory");
      __builtin_amdgcn_s_barrier();
      char* Sn = cur ? S0 : S1;
      if (k < 3) {
#pragma unroll
        for (int i = 0; i < 2; ++i) {
          int rb = i * 128 + wv * 8;
          gload16(&W2T[(size_t)(rb + lrow) * 1024 + ch * 256 + (k + 1) * 64 + kel], Sn + rb * 128);
        }
      } else if (ch < 3) {
#pragma unroll
        for (int i = 0; i < 2; ++i) {
          int rb = i * 128 + wv * 8;
          gload16(&W1T[(size_t)((ch + 1) * 256 + rb + lrow) * 256 + kel], Sn + rb * 128);
        }
      }
      char* Sc = cur ? S1 : S0;
#pragma unroll
      for (int kk = 0; kk < 2; ++kk) {
        int kb = (kk * 64 + (l4 << 4)) ^ (l7 << 4);
        int kbH = (k * 128 + kk * 64 + (l4 << 4)) ^ (l7 << 4);
        bf16x8 af[2], bfr[2];
#pragma unroll
        for (int mi = 0; mi < 2; ++mi)
          af[mi] = *(const bf16x8*)(Sc + (wr2 * 32 + mi * 16 + l15) * 128 + kb);
#pragma unroll
        for (int ni = 0; ni < 2; ++ni)
          bfr[ni] = *(const bf16x8*)(Hb + (wc2 * 32 + ni * 16 + l15) * 512 + kbH);
#pragma unroll
        for (int mi = 0; mi < 2; ++mi)
#pragma unroll
          for (int ni = 0; ni < 2; ++ni)
            acc2[mi][ni] = __builtin_amdgcn_mfma_f32_16x16x32_bf16(af[mi], bfr[ni],
                                                                   acc2[mi][ni], 0, 0, 0);
      }
      cur ^= 1;
    }
  }
  // epilogue: out[e2][c] = acc2 + b2[e2] + Y[c][e2]
  const bf16* Yb = Y + (size_t)lz * E * E;
  float* ob = out + (size_t)(batchBase + lz) * E * E;
#pragma unroll
  for (int mi = 0; mi < 2; ++mi) {
    int e2b = wr2 * 32 + mi * 16 + l4 * 4;
    f32x4 bv = *(const f32x4*)&b2[e2b];
#pragma unroll
    for (int ni = 0; ni < 2; ++ni) {
      int c = c0 + wc2 * 32 + ni * 16 + l15;
      bf16x4 yv = *(const bf16x4*)&Yb[(size_t)c * E + e2b];
#pragma unroll
      for (int r = 0; r < 4; ++r)
        ob[(size_t)(e2b + r) * E + c] = acc2[mi][ni][r] + bv[r] + (float)yv[r];
    }
  }
}

extern "C" void kernel_launch(void* const* d_in, const int* in_sizes, int n_in,
                              void* d_out, int out_size, void* d_ws, size_t ws_size,
                              hipStream_t stream) {
  const float* x = (const float*)d_in[0];
  const float* Wq = (const float*)d_in[1];
  const float* bq = (const float*)d_in[2];
  const float* Wk = (const float*)d_in[3];
  const float* bk = (const float*)d_in[4];
  const float* Wv = (const float*)d_in[5];
  const float* bv = (const float*)d_in[6];
  const float* lq1 = (const float*)d_in[7];
  const float* lk1 = (const float*)d_in[8];
  const float* lq2 = (const float*)d_in[9];
  const float* lk2 = (const float*)d_in[10];
  const float* lnattn = (const float*)d_in[11];
  const float* nscale = (const float*)d_in[12];
  const float* lnff = (const float*)d_in[13];
  const float* W1 = (const float*)d_in[14];
  const float* b1 = (const float*)d_in[15];
  const float* W2 = (const float*)d_in[16];
  const float* b2 = (const float*)d_in[17];
  float* out = (float*)d_out;

  char* ws = (char*)d_ws;
  size_t off = 0;
  auto alloc = [&](size_t bytes) {
    size_t o = off;
    off += (bytes + 255) & ~(size_t)255;
    return o;
  };
  size_t oWqT = alloc(512 * 256 * 2);
  size_t oWkT = alloc(512 * 256 * 2);
  size_t oWvT = alloc(256 * 256 * 2);
  size_t oW1T = alloc(1024 * 256 * 2);
  size_t oW2T = alloc(256 * 1024 * 2);
  size_t oLam = alloc(256);
  size_t weightEnd = off;

  const size_t szH = (size_t)E * E * 2;     // 128 KB bf16 matrix
  const size_t szQ = (size_t)E * 512 * 2;   // 256 KB bf16 [256][512]
  const size_t szRi = 1024;
  size_t perBatch = 4 * szH + 2 * szQ + szRi;
  size_t avail = ws_size > weightEnd ? ws_size - weightEnd : 0;
  int NB = (int)(avail / perBatch);
  if (NB > BTOT) NB = BTOT;
  if (NB < 1) NB = 1;

  size_t o = weightEnd;
  auto allocN = [&](size_t bytes) {
    size_t r = o;
    o += bytes * (size_t)NB;
    return r;
  };
  bf16* pA = (bf16*)(ws + allocN(szH));
  bf16* pTr = (bf16*)(ws + allocN(szH));
  bf16* pSe = (bf16*)(ws + allocN(szH));
  bf16* pVT = (bf16*)(ws + allocN(szH));
  size_t oQK = allocN(2 * szQ);             // q then k halves
  float* pRiA = (float*)(ws + allocN(szRi));

  bf16* pQ = (bf16*)(ws + oQK);
  bf16* pK = (bf16*)(ws + oQK + (size_t)NB * szQ);
  // aliases (consumed-before-written within each chunk, stream-ordered):
  bf16* pD = pTr;
  bf16* pY = pA;
  bf16* pXn = pSe;

  bf16* pWqT = (bf16*)(ws + oWqT);
  bf16* pWkT = (bf16*)(ws + oWkT);
  bf16* pWvT = (bf16*)(ws + oWvT);
  bf16* pW1T = (bf16*)(ws + oW1T);
  bf16* pW2T = (bf16*)(ws + oW2T);
  float* pLam = (float*)(ws + oLam);

  const float LAMBDA_INIT = 0.8f - 0.6f * expf(-0.3f);
  const float OML = 1.0f - LAMBDA_INIT;

  // ---- prep (once) ----
  k_wT<<<dim3((256 / 32) * (512 / 32)), 256, 0, stream>>>(Wq, pWqT, 256, 512);
  k_wT<<<dim3((256 / 32) * (512 / 32)), 256, 0, stream>>>(Wk, pWkT, 256, 512);
  k_wT<<<dim3((256 / 32) * (256 / 32)), 256, 0, stream>>>(Wv, pWvT, 256, 256);
  k_wT<<<dim3((256 / 32) * (1024 / 32)), 256, 0, stream>>>(W1, pW1T, 256, 1024);
  k_wT<<<dim3((1024 / 32) * (256 / 32)), 256, 0, stream>>>(W2, pW2T, 1024, 256);
  k_lam<<<1, 256, 0, stream>>>(lq1, lk1, lq2, lk2, LAMBDA_INIT, pLam);

  for (int base = 0; base < BTOT; base += NB) {
    int cnt = BTOT - base < NB ? BTOT - base : NB;
    k_rmsA<<<dim3(cnt), 1024, 0, stream>>>(x, base, pRiA);
    k_prep<<<dim3(8, cnt), 256, 0, stream>>>(x, base, pRiA, lnattn, pA, pTr, pSe);
    // q & k projections merged into one dispatch (independent, same shape)
    gemm_qk<<<dim3(16 * cnt), 256, 0, stream>>>(pTr, pSe, pWqT, pWkT, pQ, pK, bq, bk, cnt);
    // vT[e][c] = WvT @ a_t^T + bv[e]
    gemm_bt<2><<<dim3(2 * 2 * cnt), 256, 0, stream>>>(pWvT, 256, 0, pA, 256, 65536,
        pVT, 256, 65536, 256, nullptr, bv, 2, 2, 2 * cnt);
    // d = softmax(0.25*q1k1) - lam*softmax(0.25*q2k2)   (overwrites pTr)
    k_score<<<dim3(2 * cnt), 512, 0, stream>>>(pQ, pK, pLam, pD, cnt);
    // Y = x^T + nscale * rmsnorm_row(d@v) * (1-lam_init)   (overwrites pA)
    k_pv<<<dim3(2 * cnt), 512, 0, stream>>>(pD, pVT, x, base, nscale, OML, pY, cnt);
    // xn = lnff[c] * Y * colrms(Y)   (overwrites pSe)
    k_ffnorm<<<dim3(8, cnt), 256, 0, stream>>>(pY, lnff, pXn);
    // fused FFN: out = W2T . silu(xn.W1T^T + b1) + b2 + Y   (h1 stays in LDS)
    k_ffn<<<dim3(4 * cnt), 1024, 0, stream>>>(pXn, pW1T, pW2T, b1, b2, pY, base, out);
  }
}

// Round 12
// 514.581 us; speedup vs baseline: 1.0167x; 1.0167x over previous
//
#include <hip/hip_runtime.h>
#include <math.h>

static constexpr int E = 256;   // embed/seq/chn dim (all equal)
static constexpr int BTOT = 256;

typedef __bf16 bf16;
typedef __bf16 bf16x8 __attribute__((ext_vector_type(8)));
typedef __bf16 bf16x4 __attribute__((ext_vector_type(4)));
typedef float f32x4 __attribute__((ext_vector_type(4)));

// async global->LDS, 16B per lane. LDS dest is wave-uniform base + lane*16.
__device__ __forceinline__ void gload16(const void* g, void* l) {
  __builtin_amdgcn_global_load_lds(
      (const __attribute__((address_space(1))) void*)g,
      (__attribute__((address_space(3))) void*)l, 16, 0, 0);
}

// XCD-aware flat-grid decode (bijective iff nPanels%8==0, else identity).
__device__ __forceinline__ void xcd_decode(int b, int NX, int nPanels, int& x, int& g) {
  if ((nPanels & 7) == 0) {
    int gLo = b & 7;
    int t2 = b >> 3;
    x = t2 % NX;
    g = (t2 / NX) * 8 + gLo;
  } else {
    x = b % NX;
    g = b / NX;
  }
}

__device__ __forceinline__ float fsig(float x) {
  return __fdividef(1.0f, 1.0f + __expf(-x));
}

// ---------------- prep: weight transpose f32[R][C] -> bf16[C][R] ----------------
__global__ __launch_bounds__(256) void k_wT(const float* __restrict__ src,
                                            bf16* __restrict__ dst, int R, int C) {
  __shared__ float lds[32][33];
  int tiles_c = C >> 5;
  int tc = blockIdx.x % tiles_c;
  int tr = blockIdx.x / tiles_c;
  int r0 = tr << 5, c0 = tc << 5;
  int t = threadIdx.x, cc = t & 31, rr0 = t >> 5;
#pragma unroll
  for (int p = 0; p < 4; ++p) {
    int rr = rr0 + p * 8;
    lds[rr][cc] = src[(size_t)(r0 + rr) * C + (c0 + cc)];
  }
  __syncthreads();
#pragma unroll
  for (int p = 0; p < 4; ++p) {
    int rr = rr0 + p * 8;
    dst[(size_t)(c0 + rr) * R + (r0 + cc)] = (bf16)lds[cc][rr];
  }
}

// ---------------- prep: lambda scalar ----------------
__global__ void k_lam(const float* lq1, const float* lk1, const float* lq2,
                      const float* lk2, float lambda_init, float* lamOut) {
  int t = threadIdx.x;
  float v1 = lq1[t] * lk1[t];
  float v2 = lq2[t] * lk2[t];
  __shared__ float s1[4], s2[4];
#pragma unroll
  for (int o = 32; o; o >>= 1) { v1 += __shfl_xor(v1, o); v2 += __shfl_xor(v2, o); }
  if ((t & 63) == 0) { s1[t >> 6] = v1; s2[t >> 6] = v2; }
  __syncthreads();
  if (t == 0) {
    float a = s1[0] + s1[1] + s1[2] + s1[3];
    float b = s2[0] + s2[1] + s2[2] + s2[3];
    *lamOut = expf(a) - expf(b) + lambda_init;
  }
}

// ---------------- per-column (axis-i) RMS of x: rinvA[b][j] ----------------
__global__ __launch_bounds__(1024) void k_rmsA(const float* __restrict__ x, int batchBase,
                                               float* __restrict__ rinvA) {
  __shared__ float red[4][257];
  int lz = blockIdx.x;
  int g = batchBase + lz;
  int t = threadIdx.x, j = t & 255, qd = t >> 8;
  const float* xb = x + (size_t)g * E * E;
  float s = 0.f;
#pragma unroll 4
  for (int ii = 0; ii < 64; ++ii) {
    float v = xb[(size_t)(qd * 64 + ii) * E + j];
    s += v * v;
  }
  red[qd][j] = s;
  __syncthreads();
  if (qd == 0) {
    float tot = red[0][j] + red[1][j] + red[2][j] + red[3][j];
    rinvA[lz * E + j] = __fdividef(1.0f, sqrtf(tot) * 0.0625f + 1e-8f);
  }
}

// ---------------- fused: transpose + rmsnorm-scale + trend/seasonal ----------------
__global__ __launch_bounds__(256) void k_prep(const float* __restrict__ x, int batchBase,
                                              const float* __restrict__ rinvA,
                                              const float* __restrict__ lnattn,
                                              bf16* __restrict__ a_t,
                                              bf16* __restrict__ tr_t, bf16* __restrict__ se_t) {
  __shared__ float lA[36][261];
  int lz = blockIdx.y, g = batchBase + lz;
  int i0 = blockIdx.x << 5;
  int t = threadIdx.x;
  const float* xb = x + (size_t)g * E * E;
  float rj = rinvA[lz * E + t];
#pragma unroll
  for (int rr = 0; rr < 36; ++rr) {
    int gi = i0 - 2 + rr;
    gi = gi < 0 ? 0 : (gi > 255 ? 255 : gi);
    float v = xb[(size_t)gi * E + t];
    lA[rr][t] = lnattn[gi] * v * rj;
  }
  __syncthreads();
  size_t bo = (size_t)lz * E * E;
  int ic = t & 31, jg = t >> 5;
#pragma unroll 4
  for (int jj = 0; jj < 32; ++jj) {
    int j = jg + jj * 8;
    float a0 = lA[ic][j], a1 = lA[ic + 1][j], a2 = lA[ic + 2][j];
    float a3 = lA[ic + 3][j], a4 = lA[ic + 4][j];
    float tr = (a0 + a1 + a2 + a3 + a4) * 0.2f;
    size_t o = bo + (size_t)j * E + i0 + ic;
    a_t[o] = (bf16)a2;
    tr_t[o] = (bf16)tr;
    se_t[o] = (bf16)(a2 - tr);
  }
}

// ---------------- merged q, k, v projection GEMMs (one dispatch) -------------------
// per batch 5 panels x 4 xdec: p=0,1 -> q (mb=p*128); p=2,3 -> k; p=4 -> v
// (operand-swapped: A=WvT shared, B=a_t batched, row bias bv, out vT[e][c]).
__global__ __launch_bounds__(256) void gemm_qkv(
    const bf16* __restrict__ tr, const bf16* __restrict__ se,
    const bf16* __restrict__ a_t,
    const bf16* __restrict__ WqT, const bf16* __restrict__ WkT,
    const bf16* __restrict__ WvT,
    bf16* __restrict__ q, bf16* __restrict__ k, bf16* __restrict__ vT,
    const float* __restrict__ bq, const float* __restrict__ bk,
    const float* __restrict__ bv, int cnt) {
  __shared__ __align__(128) bf16 As[128][64];
  __shared__ __align__(128) bf16 Bs[128][64];
  int xdec, gdec;
  xcd_decode(blockIdx.x, 4, 5 * cnt, xdec, gdec);
  int lz = gdec / 5, p = gdec % 5;
  const bf16 *Ab, *Bb;
  bf16* Out;
  const float* bias;
  int mb, nb, ldo;
  bool rowBias;
  if (p < 4) {
    int sel = p >> 1;
    mb = (p & 1) << 7;
    nb = xdec << 7;
    Ab = (sel ? se : tr) + (size_t)lz * 65536;
    Bb = sel ? WkT : WqT;
    Out = (sel ? k : q) + (size_t)lz * 131072;
    bias = sel ? bk : bq;
    ldo = 512;
    rowBias = false;
  } else {
    mb = (xdec >> 1) << 7;
    nb = (xdec & 1) << 7;
    Ab = WvT;
    Bb = a_t + (size_t)lz * 65536;
    Out = vT + (size_t)lz * 65536;
    bias = bv;
    ldo = 256;
    rowBias = true;
  }
  int t = threadIdx.x, lane = t & 63, wv = t >> 6;
  int wr = wv >> 1, wc = wv & 1;
  int lrow = lane >> 3;
  int kel = ((lane & 7) ^ lrow) << 3;
  f32x4 acc[4][4];
  const f32x4 z4 = {0.f, 0.f, 0.f, 0.f};
#pragma unroll
  for (int a = 0; a < 4; ++a)
#pragma unroll
    for (int b = 0; b < 4; ++b) acc[a][b] = z4;
  for (int k0 = 0; k0 < 256; k0 += 64) {
    __syncthreads();
#pragma unroll
    for (int i = 0; i < 4; ++i) {
      int rb = i * 32 + wv * 8;
      gload16(&Ab[(size_t)(mb + rb + lrow) * 256 + k0 + kel], &As[rb][0]);
      gload16(&Bb[(size_t)(nb + rb + lrow) * 256 + k0 + kel], &Bs[rb][0]);
    }
    __syncthreads();
    __builtin_amdgcn_s_setprio(1);
#pragma unroll
    for (int kk = 0; kk < 2; ++kk) {
      int kb = (kk * 64 + ((lane >> 4) << 4)) ^ ((lane & 7) << 4);
      bf16x8 af[4], bfr[4];
#pragma unroll
      for (int mi = 0; mi < 4; ++mi)
        af[mi] = *(const bf16x8*)((const char*)As + (wr * 64 + mi * 16 + (lane & 15)) * 128 + kb);
#pragma unroll
      for (int ni = 0; ni < 4; ++ni)
        bfr[ni] = *(const bf16x8*)((const char*)Bs + (wc * 64 + ni * 16 + (lane & 15)) * 128 + kb);
#pragma unroll
      for (int mi = 0; mi < 4; ++mi)
#pragma unroll
        for (int ni = 0; ni < 4; ++ni)
          acc[mi][ni] = __builtin_amdgcn_mfma_f32_16x16x32_bf16(af[mi], bfr[ni],
                                                                acc[mi][ni], 0, 0, 0);
    }
    __builtin_amdgcn_s_setprio(0);
  }
  int colB = nb + wc * 64 + (lane & 15);
  int rowB = mb + wr * 64 + ((lane >> 4) << 2);
#pragma unroll
  for (int mi = 0; mi < 4; ++mi) {
#pragma unroll
    for (int ni = 0; ni < 4; ++ni) {
      int col = colB + ni * 16;
      float bcol = rowBias ? 0.f : bias[col];
#pragma unroll
      for (int r = 0; r < 4; ++r) {
        int row = rowB + mi * 16 + r;
        float b = rowBias ? bias[row] : bcol;
        Out[(size_t)row * ldo + col] = (bf16)(acc[mi][ni][r] + b);
      }
    }
  }
}

// ---------------- fused dual score GEMM + dual softmax + diff -> d (bf16) ----------
__global__ __launch_bounds__(512) void k_score(const bf16* __restrict__ q,
                                               const bf16* __restrict__ km,
                                               const float* __restrict__ lamPtr,
                                               bf16* __restrict__ D, int nPanels) {
  __shared__ __align__(128) bf16 As[128][64];
  __shared__ __align__(128) bf16 Bs[256][64];
  __shared__ float red[4][128];
  int xdec, lz;
  xcd_decode(blockIdx.x, 2, nPanels, xdec, lz);
  int mb = xdec << 7;
  const bf16* qb = q + (size_t)lz * E * 512;
  const bf16* kb = km + (size_t)lz * E * 512;
  int t = threadIdx.x, lane = t & 63, wv = t >> 6;
  int wr = wv >> 2, wc = wv & 3;
  int lrow = lane >> 3;
  int kel = ((lane & 7) ^ lrow) << 3;
  f32x4 acc1[4][4], acc2[4][4];
  const f32x4 z4 = {0.f, 0.f, 0.f, 0.f};
#pragma unroll
  for (int a = 0; a < 4; ++a)
#pragma unroll
    for (int b = 0; b < 4; ++b) { acc1[a][b] = z4; acc2[a][b] = z4; }
#pragma unroll
  for (int mat = 0; mat < 2; ++mat) {
    f32x4(*acc)[4] = mat == 0 ? acc1 : acc2;
    const bf16* qm = qb + mat * 256;
    const bf16* kmm = kb + mat * 256;
    for (int k0 = 0; k0 < 256; k0 += 64) {
      __syncthreads();
#pragma unroll
      for (int i = 0; i < 2; ++i) {
        int rb = i * 64 + wv * 8;
        gload16(&qm[(size_t)(mb + rb + lrow) * 512 + k0 + kel], &As[rb][0]);
      }
#pragma unroll
      for (int i = 0; i < 4; ++i) {
        int rb = i * 64 + wv * 8;
        gload16(&kmm[(size_t)(rb + lrow) * 512 + k0 + kel], &Bs[rb][0]);
      }
      __syncthreads();
      __builtin_amdgcn_s_setprio(1);
#pragma unroll
      for (int kk = 0; kk < 2; ++kk) {
        int kb2 = (kk * 64 + ((lane >> 4) << 4)) ^ ((lane & 7) << 4);
        bf16x8 af[4], bfr[4];
#pragma unroll
        for (int mi = 0; mi < 4; ++mi)
          af[mi] = *(const bf16x8*)((const char*)As + (wr * 64 + mi * 16 + (lane & 15)) * 128 + kb2);
#pragma unroll
        for (int ni = 0; ni < 4; ++ni)
          bfr[ni] = *(const bf16x8*)((const char*)Bs + (wc * 64 + ni * 16 + (lane & 15)) * 128 + kb2);
#pragma unroll
        for (int mi = 0; mi < 4; ++mi)
#pragma unroll
          for (int ni = 0; ni < 4; ++ni)
            acc[mi][ni] = __builtin_amdgcn_mfma_f32_16x16x32_bf16(af[mi], bfr[ni],
                                                                  acc[mi][ni], 0, 0, 0);
      }
      __builtin_amdgcn_s_setprio(0);
    }
  }
  float lam = *lamPtr;
  int rbase = wr * 64 + ((lane >> 4) << 2);
  float inv1[4][4], inv2[4][4];
  __syncthreads();
#pragma unroll
  for (int mat = 0; mat < 2; ++mat) {
    f32x4(*acc)[4] = mat == 0 ? acc1 : acc2;
    float(*inv)[4] = mat == 0 ? inv1 : inv2;
    float tmp[4][4];
#pragma unroll
    for (int mi = 0; mi < 4; ++mi)
#pragma unroll
      for (int r = 0; r < 4; ++r) {
        float m = fmaxf(fmaxf(acc[mi][0][r], acc[mi][1][r]),
                        fmaxf(acc[mi][2][r], acc[mi][3][r]));
        m = fmaxf(m, __shfl_xor(m, 1));
        m = fmaxf(m, __shfl_xor(m, 2));
        m = fmaxf(m, __shfl_xor(m, 4));
        m = fmaxf(m, __shfl_xor(m, 8));
        tmp[mi][r] = m;
      }
    if ((lane & 15) == 0) {
#pragma unroll
      for (int mi = 0; mi < 4; ++mi)
#pragma unroll
        for (int r = 0; r < 4; ++r) red[wc][rbase + mi * 16 + r] = tmp[mi][r];
    }
    __syncthreads();
#pragma unroll
    for (int mi = 0; mi < 4; ++mi)
#pragma unroll
      for (int r = 0; r < 4; ++r) {
        int rw = rbase + mi * 16 + r;
        tmp[mi][r] = fmaxf(fmaxf(red[0][rw], red[1][rw]), fmaxf(red[2][rw], red[3][rw]));
      }
    __syncthreads();
#pragma unroll
    for (int mi = 0; mi < 4; ++mi)
#pragma unroll
      for (int r = 0; r < 4; ++r) {
        float m = tmp[mi][r], s = 0.f;
#pragma unroll
        for (int ni = 0; ni < 4; ++ni) {
          float p = __expf(0.25f * (acc[mi][ni][r] - m));
          acc[mi][ni][r] = p;
          s += p;
        }
        s += __shfl_xor(s, 1);
        s += __shfl_xor(s, 2);
        s += __shfl_xor(s, 4);
        s += __shfl_xor(s, 8);
        tmp[mi][r] = s;
      }
    if ((lane & 15) == 0) {
#pragma unroll
      for (int mi = 0; mi < 4; ++mi)
#pragma unroll
        for (int r = 0; r < 4; ++r) red[wc][rbase + mi * 16 + r] = tmp[mi][r];
    }
    __syncthreads();
#pragma unroll
    for (int mi = 0; mi < 4; ++mi)
#pragma unroll
      for (int r = 0; r < 4; ++r) {
        int rw = rbase + mi * 16 + r;
        inv[mi][r] = __fdividef(1.0f, red[0][rw] + red[1][rw] + red[2][rw] + red[3][rw]);
      }
    __syncthreads();
  }
  size_t Dbase = (size_t)lz * E * E;
#pragma unroll
  for (int mi = 0; mi < 4; ++mi)
#pragma unroll
    for (int ni = 0; ni < 4; ++ni) {
      int col = wc * 64 + ni * 16 + (lane & 15);
#pragma unroll
      for (int r = 0; r < 4; ++r) {
        int row = mb + rbase + mi * 16 + r;
        D[Dbase + (size_t)row * E + col] =
            (bf16)(acc1[mi][ni][r] * inv1[mi][r] - lam * acc2[mi][ni][r] * inv2[mi][r]);
      }
    }
}

// ---------------- fused pre = d@v GEMM + row-rmsnorm + residual(x) -> Y (bf16) -----
__global__ __launch_bounds__(512) void k_pv(const bf16* __restrict__ Dm,
                                            const bf16* __restrict__ vT,
                                            const float* __restrict__ x, int batchBase,
                                            const float* __restrict__ nscale,
                                            float oml, bf16* __restrict__ Y, int nPanels) {
  __shared__ __align__(128) bf16 As[128][64];
  __shared__ __align__(128) bf16 Bs[256][64];
  __shared__ float red[4][128];
  int xdec, lz;
  xcd_decode(blockIdx.x, 2, nPanels, xdec, lz);
  int mb = xdec << 7;
  const bf16* Ab = Dm + (size_t)lz * E * E;
  const bf16* Bb = vT + (size_t)lz * E * E;
  int t = threadIdx.x, lane = t & 63, wv = t >> 6;
  int wr = wv >> 2, wc = wv & 3;
  int lrow = lane >> 3;
  int kel = ((lane & 7) ^ lrow) << 3;
  f32x4 acc[4][4];
  const f32x4 z4 = {0.f, 0.f, 0.f, 0.f};
#pragma unroll
  for (int a = 0; a < 4; ++a)
#pragma unroll
    for (int b = 0; b < 4; ++b) acc[a][b] = z4;
  for (int k0 = 0; k0 < 256; k0 += 64) {
    __syncthreads();
#pragma unroll
    for (int i = 0; i < 2; ++i) {
      int rb = i * 64 + wv * 8;
      gload16(&Ab[(size_t)(mb + rb + lrow) * E + k0 + kel], &As[rb][0]);
    }
#pragma unroll
    for (int i = 0; i < 4; ++i) {
      int rb = i * 64 + wv * 8;
      gload16(&Bb[(size_t)(rb + lrow) * E + k0 + kel], &Bs[rb][0]);
    }
    __syncthreads();
    __builtin_amdgcn_s_setprio(1);
#pragma unroll
    for (int kk = 0; kk < 2; ++kk) {
      int kb2 = (kk * 64 + ((lane >> 4) << 4)) ^ ((lane & 7) << 4);
      bf16x8 af[4], bfr[4];
#pragma unroll
      for (int mi = 0; mi < 4; ++mi)
        af[mi] = *(const bf16x8*)((const char*)As + (wr * 64 + mi * 16 + (lane & 15)) * 128 + kb2);
#pragma unroll
      for (int ni = 0; ni < 4; ++ni)
        bfr[ni] = *(const bf16x8*)((const char*)Bs + (wc * 64 + ni * 16 + (lane & 15)) * 128 + kb2);
#pragma unroll
      for (int mi = 0; mi < 4; ++mi)
#pragma unroll
        for (int ni = 0; ni < 4; ++ni)
          acc[mi][ni] = __builtin_amdgcn_mfma_f32_16x16x32_bf16(af[mi], bfr[ni],
                                                                acc[mi][ni], 0, 0, 0);
    }
    __builtin_amdgcn_s_setprio(0);
  }
  int rbase = wr * 64 + ((lane >> 4) << 2);
  float rowinv[4][4];
#pragma unroll
  for (int mi = 0; mi < 4; ++mi)
#pragma unroll
    for (int r = 0; r < 4; ++r) {
      float s = 0.f;
#pragma unroll
      for (int ni = 0; ni < 4; ++ni) {
        float v = acc[mi][ni][r];
        s += v * v;
      }
      s += __shfl_xor(s, 1);
      s += __shfl_xor(s, 2);
      s += __shfl_xor(s, 4);
      s += __shfl_xor(s, 8);
      rowinv[mi][r] = s;
    }
  if ((lane & 15) == 0) {
#pragma unroll
    for (int mi = 0; mi < 4; ++mi)
#pragma unroll
      for (int r = 0; r < 4; ++r) red[wc][rbase + mi * 16 + r] = rowinv[mi][r];
  }
  __syncthreads();
#pragma unroll
  for (int mi = 0; mi < 4; ++mi)
#pragma unroll
    for (int r = 0; r < 4; ++r) {
      int rw = rbase + mi * 16 + r;
      float tot = red[0][rw] + red[1][rw] + red[2][rw] + red[3][rw];
      rowinv[mi][r] = oml * __fdividef(1.0f, sqrtf(tot) * 0.0625f + 1e-8f);
    }
  size_t bo = (size_t)lz * E * E;
  const float* xb = x + (size_t)(batchBase + lz) * E * E;
#pragma unroll
  for (int mi = 0; mi < 4; ++mi)
#pragma unroll
    for (int ni = 0; ni < 4; ++ni) {
      int col = wc * 64 + ni * 16 + (lane & 15);
      float ns = nscale[col];
      int row0 = mb + rbase + mi * 16;
      f32x4 xv = *(const f32x4*)&xb[(size_t)col * E + row0];
#pragma unroll
      for (int r = 0; r < 4; ++r) {
        size_t o = bo + (size_t)(row0 + r) * E + col;
        Y[o] = (bf16)(xv[r] + ns * acc[mi][ni][r] * rowinv[mi][r]);
      }
    }
}

// ---------------- fused column-RMS of Y + scale -> xn (bf16) ----------------------
__global__ __launch_bounds__(256) void k_ffnorm(const bf16* __restrict__ Y,
                                                const float* __restrict__ lnff,
                                                bf16* __restrict__ xn) {
  __shared__ float red[8][33];
  __shared__ float rl[32];
  int lz = blockIdx.y;
  int i0 = blockIdx.x << 5;
  int t = threadIdx.x, ic = t & 31, jg = t >> 5;
  size_t bo = (size_t)lz * E * E;
  float s = 0.f;
#pragma unroll 4
  for (int jj = 0; jj < 32; ++jj) {
    int j = jg + jj * 8;
    float v = (float)Y[bo + (size_t)j * E + i0 + ic];
    s += v * v;
  }
  red[jg][ic] = s;
  __syncthreads();
  if (jg == 0) {
    float tot = 0.f;
#pragma unroll
    for (int g2 = 0; g2 < 8; ++g2) tot += red[g2][ic];
    rl[ic] = __fdividef(1.0f, sqrtf(tot) * 0.0625f + 1e-8f);
  }
  __syncthreads();
  float rinv = rl[ic];
#pragma unroll 4
  for (int jj = 0; jj < 32; ++jj) {
    int j = jg + jj * 8;
    size_t o = bo + (size_t)j * E + i0 + ic;
    xn[o] = (bf16)(lnff[j] * (float)Y[o] * rinv);
  }
}

// ---------------- fused FFN (round-6 schedule: issue-early + vmcnt(2), 2 barriers) -
__global__ __launch_bounds__(1024) void k_ffn(const bf16* __restrict__ xn,
                                              const bf16* __restrict__ W1T,
                                              const bf16* __restrict__ W2T,
                                              const float* __restrict__ b1,
                                              const float* __restrict__ b2,
                                              const bf16* __restrict__ Y,
                                              int batchBase, float* __restrict__ out) {
  __shared__ __align__(128) char arena[131072];
  char* Hb = arena;               // 32 KB: H-chunk [64 c][256 e1], eb^(c&7) swizzle
  char* xnL = arena + 32768;      // 32 KB: xn tile as [4 ksub][64 c][64 k]
  char* S0 = arena + 65536;       // 32 KB staging dbuf
  char* S1 = arena + 98304;       // 32 KB
  int bid = blockIdx.x;
  int lz = bid >> 2;
  int c0 = (bid & 3) << 6;
  const bf16* xb = xn + (size_t)lz * E * E + (size_t)c0 * E;
  int t = threadIdx.x, lane = t & 63, wv = t >> 6;
  int lrow = lane >> 3;
  int kel = ((lane & 7) ^ lrow) << 3;
  int l15 = lane & 15, l4 = lane >> 4, l7 = lane & 7;
  int wr1 = wv >> 3, wc1 = wv & 7;   // ph1: 2(M=c64) x 8(N=e1-256)
  int wr2 = wv >> 1, wc2 = wv & 1;   // ph2: 8(M=e2-256) x 2(N=c64)

  float b1v[4][2];
#pragma unroll
  for (int ch = 0; ch < 4; ++ch)
#pragma unroll
    for (int ni = 0; ni < 2; ++ni)
      b1v[ch][ni] = b1[ch * 256 + wc1 * 32 + ni * 16 + l15];

#pragma unroll
  for (int j = 0; j < 2; ++j) {
    int lin = wv * 2 + j;
    int ksub = lin >> 3, rg = (lin & 7) * 8;
    gload16(&xb[(size_t)(rg + lrow) * E + ksub * 64 + kel], xnL + ksub * 8192 + rg * 128);
  }
#pragma unroll
  for (int i = 0; i < 2; ++i) {
    int rb = i * 128 + wv * 8;
    gload16(&W1T[(size_t)(rb + lrow) * 256 + kel], S0 + rb * 128);
  }

  f32x4 acc2[2][2];
  const f32x4 z4 = {0.f, 0.f, 0.f, 0.f};
  acc2[0][0] = z4; acc2[0][1] = z4; acc2[1][0] = z4; acc2[1][1] = z4;
  int cur = 0;

  for (int ch = 0; ch < 4; ++ch) {
    f32x4 acc1[2][2];
    acc1[0][0] = z4; acc1[0][1] = z4; acc1[1][0] = z4; acc1[1][1] = z4;
    for (int k = 0; k < 4; ++k) {
      char* Sn = cur ? S0 : S1;
      if (k < 3) {
#pragma unroll
        for (int i = 0; i < 2; ++i) {
          int rb = i * 128 + wv * 8;
          gload16(&W1T[(size_t)(ch * 256 + rb + lrow) * 256 + (k + 1) * 64 + kel], Sn + rb * 128);
        }
      } else {
#pragma unroll
        for (int i = 0; i < 2; ++i) {
          int rb = i * 128 + wv * 8;
          gload16(&W2T[(size_t)(rb + lrow) * 1024 + ch * 256 + kel], Sn + rb * 128);
        }
      }
      asm volatile("s_waitcnt vmcnt(2)" ::: "memory");
      __builtin_amdgcn_s_barrier();
      char* Sc = cur ? S1 : S0;
#pragma unroll
      for (int kk = 0; kk < 2; ++kk) {
        int kb = (kk * 64 + (l4 << 4)) ^ (l7 << 4);
        bf16x8 af[2], bfr[2];
#pragma unroll
        for (int mi = 0; mi < 2; ++mi)
          af[mi] = *(const bf16x8*)(xnL + k * 8192 + (wr1 * 32 + mi * 16 + l15) * 128 + kb);
#pragma unroll
        for (int ni = 0; ni < 2; ++ni)
          bfr[ni] = *(const bf16x8*)(Sc + (wc1 * 32 + ni * 16 + l15) * 128 + kb);
#pragma unroll
        for (int mi = 0; mi < 2; ++mi)
#pragma unroll
          for (int ni = 0; ni < 2; ++ni)
            acc1[mi][ni] = __builtin_amdgcn_mfma_f32_16x16x32_bf16(af[mi], bfr[ni],
                                                                   acc1[mi][ni], 0, 0, 0);
      }
      __builtin_amdgcn_s_barrier();
      cur ^= 1;
    }
#pragma unroll
    for (int mi = 0; mi < 2; ++mi)
#pragma unroll
      for (int ni = 0; ni < 2; ++ni) {
        int e1 = wc1 * 32 + ni * 16 + l15;
        float bN = b1v[ch][ni];
#pragma unroll
        for (int r = 0; r < 4; ++r) {
          int c = wr1 * 32 + mi * 16 + l4 * 4 + r;
          float u = acc1[mi][ni][r] + bN;
          float h = u * fsig(u);
          int bo2 = c * 512 + ((((e1 >> 3) ^ (c & 7)) << 4) | ((e1 & 7) * 2));
          *(bf16*)(Hb + bo2) = (bf16)h;
        }
      }
    asm volatile("s_waitcnt lgkmcnt(0)" ::: "memory");
    for (int k = 0; k < 4; ++k) {
      char* Sn = cur ? S0 : S1;
      bool isLast = (ch == 3) && (k == 3);
      if (k < 3) {
#pragma unroll
        for (int i = 0; i < 2; ++i) {
          int rb = i * 128 + wv * 8;
          gload16(&W2T[(size_t)(rb + lrow) * 1024 + ch * 256 + (k + 1) * 64 + kel], Sn + rb * 128);
        }
      } else if (ch < 3) {
#pragma unroll
        for (int i = 0; i < 2; ++i) {
          int rb = i * 128 + wv * 8;
          gload16(&W1T[(size_t)((ch + 1) * 256 + rb + lrow) * 256 + kel], Sn + rb * 128);
        }
      }
      if (isLast) asm volatile("s_waitcnt vmcnt(0)" ::: "memory");
      else        asm volatile("s_waitcnt vmcnt(2)" ::: "memory");
      __builtin_amdgcn_s_barrier();
      char* Sc = cur ? S1 : S0;
#pragma unroll
      for (int kk = 0; kk < 2; ++kk) {
        int kb = (kk * 64 + (l4 << 4)) ^ (l7 << 4);
        int kbH = (k * 128 + kk * 64 + (l4 << 4)) ^ (l7 << 4);
        bf16x8 af[2], bfr[2];
#pragma unroll
        for (int mi = 0; mi < 2; ++mi)
          af[mi] = *(const bf16x8*)(Sc + (wr2 * 32 + mi * 16 + l15) * 128 + kb);
#pragma unroll
        for (int ni = 0; ni < 2; ++ni)
          bfr[ni] = *(const bf16x8*)(Hb + (wc2 * 32 + ni * 16 + l15) * 512 + kbH);
#pragma unroll
        for (int mi = 0; mi < 2; ++mi)
#pragma unroll
          for (int ni = 0; ni < 2; ++ni)
            acc2[mi][ni] = __builtin_amdgcn_mfma_f32_16x16x32_bf16(af[mi], bfr[ni],
                                                                   acc2[mi][ni], 0, 0, 0);
      }
      __builtin_amdgcn_s_barrier();
      cur ^= 1;
    }
  }
  const bf16* Yb = Y + (size_t)lz * E * E;
  float* ob = out + (size_t)(batchBase + lz) * E * E;
#pragma unroll
  for (int mi = 0; mi < 2; ++mi) {
    int e2b = wr2 * 32 + mi * 16 + l4 * 4;
    f32x4 bv = *(const f32x4*)&b2[e2b];
#pragma unroll
    for (int ni = 0; ni < 2; ++ni) {
      int c = c0 + wc2 * 32 + ni * 16 + l15;
      bf16x4 yv = *(const bf16x4*)&Yb[(size_t)c * E + e2b];
#pragma unroll
      for (int r = 0; r < 4; ++r)
        ob[(size_t)(e2b + r) * E + c] = acc2[mi][ni][r] + bv[r] + (float)yv[r];
    }
  }
}

extern "C" void kernel_launch(void* const* d_in, const int* in_sizes, int n_in,
                              void* d_out, int out_size, void* d_ws, size_t ws_size,
                              hipStream_t stream) {
  const float* x = (const float*)d_in[0];
  const float* Wq = (const float*)d_in[1];
  const float* bq = (const float*)d_in[2];
  const float* Wk = (const float*)d_in[3];
  const float* bk = (const float*)d_in[4];
  const float* Wv = (const float*)d_in[5];
  const float* bv = (const float*)d_in[6];
  const float* lq1 = (const float*)d_in[7];
  const float* lk1 = (const float*)d_in[8];
  const float* lq2 = (const float*)d_in[9];
  const float* lk2 = (const float*)d_in[10];
  const float* lnattn = (const float*)d_in[11];
  const float* nscale = (const float*)d_in[12];
  const float* lnff = (const float*)d_in[13];
  const float* W1 = (const float*)d_in[14];
  const float* b1 = (const float*)d_in[15];
  const float* W2 = (const float*)d_in[16];
  const float* b2 = (const float*)d_in[17];
  float* out = (float*)d_out;

  char* ws = (char*)d_ws;
  size_t off = 0;
  auto alloc = [&](size_t bytes) {
    size_t o = off;
    off += (bytes + 255) & ~(size_t)255;
    return o;
  };
  size_t oWqT = alloc(512 * 256 * 2);
  size_t oWkT = alloc(512 * 256 * 2);
  size_t oWvT = alloc(256 * 256 * 2);
  size_t oW1T = alloc(1024 * 256 * 2);
  size_t oW2T = alloc(256 * 1024 * 2);
  size_t oLam = alloc(256);
  size_t weightEnd = off;

  const size_t szH = (size_t)E * E * 2;     // 128 KB bf16 matrix
  const size_t szQ = (size_t)E * 512 * 2;   // 256 KB bf16 [256][512]
  const size_t szRi = 1024;
  size_t perBatch = 4 * szH + 2 * szQ + szRi;
  size_t avail = ws_size > weightEnd ? ws_size - weightEnd : 0;
  int NB = (int)(avail / perBatch);
  if (NB > BTOT) NB = BTOT;
  if (NB < 1) NB = 1;

  size_t o = weightEnd;
  auto allocN = [&](size_t bytes) {
    size_t r = o;
    o += bytes * (size_t)NB;
    return r;
  };
  bf16* pA = (bf16*)(ws + allocN(szH));
  bf16* pTr = (bf16*)(ws + allocN(szH));
  bf16* pSe = (bf16*)(ws + allocN(szH));
  bf16* pVT = (bf16*)(ws + allocN(szH));
  size_t oQK = allocN(2 * szQ);             // q then k halves
  float* pRiA = (float*)(ws + allocN(szRi));

  bf16* pQ = (bf16*)(ws + oQK);
  bf16* pK = (bf16*)(ws + oQK + (size_t)NB * szQ);
  // aliases (consumed-before-written within each chunk, stream-ordered):
  bf16* pD = pTr;
  bf16* pY = pA;
  bf16* pXn = pSe;

  bf16* pWqT = (bf16*)(ws + oWqT);
  bf16* pWkT = (bf16*)(ws + oWkT);
  bf16* pWvT = (bf16*)(ws + oWvT);
  bf16* pW1T = (bf16*)(ws + oW1T);
  bf16* pW2T = (bf16*)(ws + oW2T);
  float* pLam = (float*)(ws + oLam);

  const float LAMBDA_INIT = 0.8f - 0.6f * expf(-0.3f);
  const float OML = 1.0f - LAMBDA_INIT;

  // ---- prep (once) ----
  k_wT<<<dim3((256 / 32) * (512 / 32)), 256, 0, stream>>>(Wq, pWqT, 256, 512);
  k_wT<<<dim3((256 / 32) * (512 / 32)), 256, 0, stream>>>(Wk, pWkT, 256, 512);
  k_wT<<<dim3((256 / 32) * (256 / 32)), 256, 0, stream>>>(Wv, pWvT, 256, 256);
  k_wT<<<dim3((256 / 32) * (1024 / 32)), 256, 0, stream>>>(W1, pW1T, 256, 1024);
  k_wT<<<dim3((1024 / 32) * (256 / 32)), 256, 0, stream>>>(W2, pW2T, 1024, 256);
  k_lam<<<1, 256, 0, stream>>>(lq1, lk1, lq2, lk2, LAMBDA_INIT, pLam);

  for (int base = 0; base < BTOT; base += NB) {
    int cnt = BTOT - base < NB ? BTOT - base : NB;
    k_rmsA<<<dim3(cnt), 1024, 0, stream>>>(x, base, pRiA);
    k_prep<<<dim3(8, cnt), 256, 0, stream>>>(x, base, pRiA, lnattn, pA, pTr, pSe);
    // q, k, v projections merged into ONE dispatch (20 blocks/batch)
    gemm_qkv<<<dim3(20 * cnt), 256, 0, stream>>>(pTr, pSe, pA, pWqT, pWkT, pWvT,
                                                 pQ, pK, pVT, bq, bk, bv, cnt);
    // d = softmax(0.25*q1k1) - lam*softmax(0.25*q2k2)   (overwrites pTr)
    k_score<<<dim3(2 * cnt), 512, 0, stream>>>(pQ, pK, pLam, pD, cnt);
    // Y = x^T + nscale * rmsnorm_row(d@v) * (1-lam_init)   (overwrites pA)
    k_pv<<<dim3(2 * cnt), 512, 0, stream>>>(pD, pVT, x, base, nscale, OML, pY, cnt);
    // xn = lnff[c] * Y * colrms(Y)   (overwrites pSe)
    k_ffnorm<<<dim3(8, cnt), 256, 0, stream>>>(pY, lnff, pXn);
    // fused FFN: out = W2T . silu(xn.W1T^T + b1) + b2 + Y   (h1 stays in LDS)
    k_ffn<<<dim3(4 * cnt), 1024, 0, stream>>>(pXn, pW1T, pW2T, b1, b2, pY, base, out);
  }
}

// Round 13
// 485.401 us; speedup vs baseline: 1.0778x; 1.0601x over previous
//
#include <hip/hip_runtime.h>
#include <math.h>

static constexpr int E = 256;   // embed/seq/chn dim (all equal)
static constexpr int BTOT = 256;

typedef __bf16 bf16;
typedef __bf16 bf16x8 __attribute__((ext_vector_type(8)));
typedef __bf16 bf16x4 __attribute__((ext_vector_type(4)));
typedef float f32x4 __attribute__((ext_vector_type(4)));

// async global->LDS, 16B per lane. LDS dest is wave-uniform base + lane*16.
__device__ __forceinline__ void gload16(const void* g, void* l) {
  __builtin_amdgcn_global_load_lds(
      (const __attribute__((address_space(1))) void*)g,
      (__attribute__((address_space(3))) void*)l, 16, 0, 0);
}

// XCD-aware flat-grid decode (bijective iff nPanels%8==0, else identity).
__device__ __forceinline__ void xcd_decode(int b, int NX, int nPanels, int& x, int& g) {
  if ((nPanels & 7) == 0) {
    int gLo = b & 7;
    int t2 = b >> 3;
    x = t2 % NX;
    g = (t2 / NX) * 8 + gLo;
  } else {
    x = b % NX;
    g = b / NX;
  }
}

__device__ __forceinline__ float fsig(float x) {
  return __fdividef(1.0f, 1.0f + __expf(-x));
}

// ---------------- prep: weight transpose f32[R][C] -> bf16[C][R] ----------------
__global__ __launch_bounds__(256) void k_wT(const float* __restrict__ src,
                                            bf16* __restrict__ dst, int R, int C) {
  __shared__ float lds[32][33];
  int tiles_c = C >> 5;
  int tc = blockIdx.x % tiles_c;
  int tr = blockIdx.x / tiles_c;
  int r0 = tr << 5, c0 = tc << 5;
  int t = threadIdx.x, cc = t & 31, rr0 = t >> 5;
#pragma unroll
  for (int p = 0; p < 4; ++p) {
    int rr = rr0 + p * 8;
    lds[rr][cc] = src[(size_t)(r0 + rr) * C + (c0 + cc)];
  }
  __syncthreads();
#pragma unroll
  for (int p = 0; p < 4; ++p) {
    int rr = rr0 + p * 8;
    dst[(size_t)(c0 + rr) * R + (r0 + cc)] = (bf16)lds[cc][rr];
  }
}

// ---------------- prep: lambda scalar ----------------
__global__ void k_lam(const float* lq1, const float* lk1, const float* lq2,
                      const float* lk2, float lambda_init, float* lamOut) {
  int t = threadIdx.x;
  float v1 = lq1[t] * lk1[t];
  float v2 = lq2[t] * lk2[t];
  __shared__ float s1[4], s2[4];
#pragma unroll
  for (int o = 32; o; o >>= 1) { v1 += __shfl_xor(v1, o); v2 += __shfl_xor(v2, o); }
  if ((t & 63) == 0) { s1[t >> 6] = v1; s2[t >> 6] = v2; }
  __syncthreads();
  if (t == 0) {
    float a = s1[0] + s1[1] + s1[2] + s1[3];
    float b = s2[0] + s2[1] + s2[2] + s2[3];
    *lamOut = expf(a) - expf(b) + lambda_init;
  }
}

// ---------------- per-column (axis-i) RMS of x: rinvA[b][j] ----------------
__global__ __launch_bounds__(1024) void k_rmsA(const float* __restrict__ x, int batchBase,
                                               float* __restrict__ rinvA) {
  __shared__ float red[4][257];
  int lz = blockIdx.x;
  int g = batchBase + lz;
  int t = threadIdx.x, j = t & 255, qd = t >> 8;
  const float* xb = x + (size_t)g * E * E;
  float s = 0.f;
#pragma unroll 4
  for (int ii = 0; ii < 64; ++ii) {
    float v = xb[(size_t)(qd * 64 + ii) * E + j];
    s += v * v;
  }
  red[qd][j] = s;
  __syncthreads();
  if (qd == 0) {
    float tot = red[0][j] + red[1][j] + red[2][j] + red[3][j];
    rinvA[lz * E + j] = __fdividef(1.0f, sqrtf(tot) * 0.0625f + 1e-8f);
  }
}

// ---------------- fused: transpose + rmsnorm-scale + trend/seasonal ----------------
__global__ __launch_bounds__(256) void k_prep(const float* __restrict__ x, int batchBase,
                                              const float* __restrict__ rinvA,
                                              const float* __restrict__ lnattn,
                                              bf16* __restrict__ a_t,
                                              bf16* __restrict__ tr_t, bf16* __restrict__ se_t) {
  __shared__ float lA[36][261];
  int lz = blockIdx.y, g = batchBase + lz;
  int i0 = blockIdx.x << 5;
  int t = threadIdx.x;
  const float* xb = x + (size_t)g * E * E;
  float rj = rinvA[lz * E + t];
#pragma unroll
  for (int rr = 0; rr < 36; ++rr) {
    int gi = i0 - 2 + rr;
    gi = gi < 0 ? 0 : (gi > 255 ? 255 : gi);
    float v = xb[(size_t)gi * E + t];
    lA[rr][t] = lnattn[gi] * v * rj;
  }
  __syncthreads();
  size_t bo = (size_t)lz * E * E;
  int ic = t & 31, jg = t >> 5;
#pragma unroll 4
  for (int jj = 0; jj < 32; ++jj) {
    int j = jg + jj * 8;
    float a0 = lA[ic][j], a1 = lA[ic + 1][j], a2 = lA[ic + 2][j];
    float a3 = lA[ic + 3][j], a4 = lA[ic + 4][j];
    float tr = (a0 + a1 + a2 + a3 + a4) * 0.2f;
    size_t o = bo + (size_t)j * E + i0 + ic;
    a_t[o] = (bf16)a2;
    tr_t[o] = (bf16)tr;
    se_t[o] = (bf16)(a2 - tr);
  }
}

// ---------------- merged q & k projection GEMMs (one dispatch) --------------------
__global__ __launch_bounds__(256) void gemm_qk(
    const bf16* __restrict__ A1, const bf16* __restrict__ A2,
    const bf16* __restrict__ B1, const bf16* __restrict__ B2,
    bf16* __restrict__ O1, bf16* __restrict__ O2,
    const float* __restrict__ bias1, const float* __restrict__ bias2, int cnt) {
  __shared__ __align__(128) bf16 As[128][64];
  __shared__ __align__(128) bf16 Bs[128][64];
  int xdec, gdec;
  xcd_decode(blockIdx.x, 4, 4 * cnt, xdec, gdec);
  int lz = gdec >> 2;
  int sel = (gdec >> 1) & 1;
  int mb = (gdec & 1) << 7, nb = xdec << 7;
  const bf16* Ab = (sel ? A2 : A1) + (size_t)lz * 65536;
  const bf16* Bb = sel ? B2 : B1;
  bf16* Out = (sel ? O2 : O1) + (size_t)lz * 131072;
  const float* biasN = sel ? bias2 : bias1;
  int t = threadIdx.x, lane = t & 63, wv = t >> 6;
  int wr = wv >> 1, wc = wv & 1;
  int lrow = lane >> 3;
  int kel = ((lane & 7) ^ lrow) << 3;
  f32x4 acc[4][4];
  const f32x4 z4 = {0.f, 0.f, 0.f, 0.f};
#pragma unroll
  for (int a = 0; a < 4; ++a)
#pragma unroll
    for (int b = 0; b < 4; ++b) acc[a][b] = z4;
  for (int k0 = 0; k0 < 256; k0 += 64) {
    __syncthreads();
#pragma unroll
    for (int i = 0; i < 4; ++i) {
      int rb = i * 32 + wv * 8;
      gload16(&Ab[(size_t)(mb + rb + lrow) * 256 + k0 + kel], &As[rb][0]);
      gload16(&Bb[(size_t)(nb + rb + lrow) * 256 + k0 + kel], &Bs[rb][0]);
    }
    __syncthreads();
    __builtin_amdgcn_s_setprio(1);
#pragma unroll
    for (int kk = 0; kk < 2; ++kk) {
      int kb = (kk * 64 + ((lane >> 4) << 4)) ^ ((lane & 7) << 4);
      bf16x8 af[4], bfr[4];
#pragma unroll
      for (int mi = 0; mi < 4; ++mi)
        af[mi] = *(const bf16x8*)((const char*)As + (wr * 64 + mi * 16 + (lane & 15)) * 128 + kb);
#pragma unroll
      for (int ni = 0; ni < 4; ++ni)
        bfr[ni] = *(const bf16x8*)((const char*)Bs + (wc * 64 + ni * 16 + (lane & 15)) * 128 + kb);
#pragma unroll
      for (int mi = 0; mi < 4; ++mi)
#pragma unroll
        for (int ni = 0; ni < 4; ++ni)
          acc[mi][ni] = __builtin_amdgcn_mfma_f32_16x16x32_bf16(af[mi], bfr[ni],
                                                                acc[mi][ni], 0, 0, 0);
    }
    __builtin_amdgcn_s_setprio(0);
  }
  int colB = nb + wc * 64 + (lane & 15);
  int rowB = mb + wr * 64 + ((lane >> 4) << 2);
#pragma unroll
  for (int mi = 0; mi < 4; ++mi) {
#pragma unroll
    for (int ni = 0; ni < 4; ++ni) {
      int col = colB + ni * 16;
      float bN = biasN[col];
#pragma unroll
      for (int r = 0; r < 4; ++r) {
        int row = rowB + mi * 16 + r;
        Out[(size_t)row * 512 + col] = (bf16)(acc[mi][ni][r] + bN);
      }
    }
  }
}

// ---------------- BT GEMM (used for v projection): EPI=2 bf16 out + biasM ---------
template <int EPI>
__global__ __launch_bounds__(256) void gemm_bt(
    const bf16* __restrict__ A, int lda, size_t aStride,
    const bf16* __restrict__ B, int ldb, size_t bStride,
    bf16* __restrict__ Out, int ldo, size_t oStride, int K,
    const float* __restrict__ biasN, const float* __restrict__ biasM,
    int NX, int NY, int nPanels) {
  __shared__ __align__(128) bf16 As[128][64];
  __shared__ __align__(128) bf16 Bs[128][64];
  int xdec, gdec;
  xcd_decode(blockIdx.x, NX, nPanels, xdec, gdec);
  int lz = gdec / NY;
  int mb = (gdec % NY) << 7, nb = xdec << 7;
  const bf16* Ab = A + (size_t)lz * aStride;
  const bf16* Bb = B + (size_t)lz * bStride;
  int t = threadIdx.x, lane = t & 63, wv = t >> 6;
  int wr = wv >> 1, wc = wv & 1;
  int lrow = lane >> 3;
  int kel = ((lane & 7) ^ lrow) << 3;
  f32x4 acc[4][4];
  const f32x4 z4 = {0.f, 0.f, 0.f, 0.f};
#pragma unroll
  for (int a = 0; a < 4; ++a)
#pragma unroll
    for (int b = 0; b < 4; ++b) acc[a][b] = z4;
  for (int k0 = 0; k0 < K; k0 += 64) {
    __syncthreads();
#pragma unroll
    for (int i = 0; i < 4; ++i) {
      int rb = i * 32 + wv * 8;
      gload16(&Ab[(size_t)(mb + rb + lrow) * lda + k0 + kel], &As[rb][0]);
      gload16(&Bb[(size_t)(nb + rb + lrow) * ldb + k0 + kel], &Bs[rb][0]);
    }
    __syncthreads();
    __builtin_amdgcn_s_setprio(1);
#pragma unroll
    for (int kk = 0; kk < 2; ++kk) {
      int kb = (kk * 64 + ((lane >> 4) << 4)) ^ ((lane & 7) << 4);
      bf16x8 af[4], bfr[4];
#pragma unroll
      for (int mi = 0; mi < 4; ++mi)
        af[mi] = *(const bf16x8*)((const char*)As + (wr * 64 + mi * 16 + (lane & 15)) * 128 + kb);
#pragma unroll
      for (int ni = 0; ni < 4; ++ni)
        bfr[ni] = *(const bf16x8*)((const char*)Bs + (wc * 64 + ni * 16 + (lane & 15)) * 128 + kb);
#pragma unroll
      for (int mi = 0; mi < 4; ++mi)
#pragma unroll
        for (int ni = 0; ni < 4; ++ni)
          acc[mi][ni] = __builtin_amdgcn_mfma_f32_16x16x32_bf16(af[mi], bfr[ni],
                                                                acc[mi][ni], 0, 0, 0);
    }
    __builtin_amdgcn_s_setprio(0);
  }
  int colB = nb + wc * 64 + (lane & 15);
  int rowB = mb + wr * 64 + ((lane >> 4) << 2);
#pragma unroll
  for (int mi = 0; mi < 4; ++mi) {
#pragma unroll
    for (int ni = 0; ni < 4; ++ni) {
      int col = colB + ni * 16;
      float bN = 0.f;
      if constexpr (EPI == 1) bN = biasN[col];
#pragma unroll
      for (int r = 0; r < 4; ++r) {
        int row = rowB + mi * 16 + r;
        float v = acc[mi][ni][r];
        if constexpr (EPI == 1) {
          Out[(size_t)lz * oStride + (size_t)row * ldo + col] = (bf16)(v + bN);
        } else {
          Out[(size_t)lz * oStride + (size_t)row * ldo + col] = (bf16)(v + biasM[row]);
        }
      }
    }
  }
}

// ---------------- fused attention: dual score GEMM + softmax-diff (P in LDS)
//                  + PV GEMM + row-rmsnorm + residual(x) -> Y (bf16) ---------------
// block: rows [mb, mb+128) of one batch; 512 threads (8 waves, 2 wr x 4 wc).
// P never touches HBM: written to a 64 KB LDS buffer with ^((c&7)<<4) row swizzle.
__global__ __launch_bounds__(512) void k_attn(const bf16* __restrict__ q,
                                              const bf16* __restrict__ km,
                                              const bf16* __restrict__ vT,
                                              const float* __restrict__ x, int batchBase,
                                              const float* __restrict__ nscale,
                                              const float* __restrict__ lamPtr, float oml,
                                              bf16* __restrict__ Y, int nPanels) {
  __shared__ __align__(128) bf16 As[128][64];   // 16 KB (QK A staging)
  __shared__ __align__(128) bf16 Bs[256][64];   // 32 KB (QK B / PV V staging)
  __shared__ float red[4][128];                 // 2 KB
  __shared__ __align__(128) char Pb[65536];     // 64 KB: P [128 c][256 d]
  int xdec, lz;
  xcd_decode(blockIdx.x, 2, nPanels, xdec, lz);
  int mb = xdec << 7;
  const bf16* qb = q + (size_t)lz * E * 512;
  const bf16* kb = km + (size_t)lz * E * 512;
  int t = threadIdx.x, lane = t & 63, wv = t >> 6;
  int wr = wv >> 2, wc = wv & 3;
  int lrow = lane >> 3;
  int kel = ((lane & 7) ^ lrow) << 3;
  int l15 = lane & 15, l4 = lane >> 4;
  f32x4 acc1[4][4], acc2[4][4];
  const f32x4 z4 = {0.f, 0.f, 0.f, 0.f};
#pragma unroll
  for (int a = 0; a < 4; ++a)
#pragma unroll
    for (int b = 0; b < 4; ++b) { acc1[a][b] = z4; acc2[a][b] = z4; }
  // ---- QK^T phase (both score matrices, sequential) ----
#pragma unroll
  for (int mat = 0; mat < 2; ++mat) {
    f32x4(*acc)[4] = mat == 0 ? acc1 : acc2;
    const bf16* qm = qb + mat * 256;
    const bf16* kmm = kb + mat * 256;
    for (int k0 = 0; k0 < 256; k0 += 64) {
      __syncthreads();
#pragma unroll
      for (int i = 0; i < 2; ++i) {
        int rb = i * 64 + wv * 8;
        gload16(&qm[(size_t)(mb + rb + lrow) * 512 + k0 + kel], &As[rb][0]);
      }
#pragma unroll
      for (int i = 0; i < 4; ++i) {
        int rb = i * 64 + wv * 8;
        gload16(&kmm[(size_t)(rb + lrow) * 512 + k0 + kel], &Bs[rb][0]);
      }
      __syncthreads();
      __builtin_amdgcn_s_setprio(1);
#pragma unroll
      for (int kk = 0; kk < 2; ++kk) {
        int kb2 = (kk * 64 + (l4 << 4)) ^ ((lane & 7) << 4);
        bf16x8 af[4], bfr[4];
#pragma unroll
        for (int mi = 0; mi < 4; ++mi)
          af[mi] = *(const bf16x8*)((const char*)As + (wr * 64 + mi * 16 + l15) * 128 + kb2);
#pragma unroll
        for (int ni = 0; ni < 4; ++ni)
          bfr[ni] = *(const bf16x8*)((const char*)Bs + (wc * 64 + ni * 16 + l15) * 128 + kb2);
#pragma unroll
        for (int mi = 0; mi < 4; ++mi)
#pragma unroll
          for (int ni = 0; ni < 4; ++ni)
            acc[mi][ni] = __builtin_amdgcn_mfma_f32_16x16x32_bf16(af[mi], bfr[ni],
                                                                  acc[mi][ni], 0, 0, 0);
      }
      __builtin_amdgcn_s_setprio(0);
    }
  }
  // ---- dual softmax ----
  float lam = *lamPtr;
  int rbase = wr * 64 + (l4 << 2);
  float inv1[4][4], inv2[4][4];
  __syncthreads();
#pragma unroll
  for (int mat = 0; mat < 2; ++mat) {
    f32x4(*acc)[4] = mat == 0 ? acc1 : acc2;
    float(*inv)[4] = mat == 0 ? inv1 : inv2;
    float tmp[4][4];
#pragma unroll
    for (int mi = 0; mi < 4; ++mi)
#pragma unroll
      for (int r = 0; r < 4; ++r) {
        float m = fmaxf(fmaxf(acc[mi][0][r], acc[mi][1][r]),
                        fmaxf(acc[mi][2][r], acc[mi][3][r]));
        m = fmaxf(m, __shfl_xor(m, 1));
        m = fmaxf(m, __shfl_xor(m, 2));
        m = fmaxf(m, __shfl_xor(m, 4));
        m = fmaxf(m, __shfl_xor(m, 8));
        tmp[mi][r] = m;
      }
    if (l15 == 0) {
#pragma unroll
      for (int mi = 0; mi < 4; ++mi)
#pragma unroll
        for (int r = 0; r < 4; ++r) red[wc][rbase + mi * 16 + r] = tmp[mi][r];
    }
    __syncthreads();
#pragma unroll
    for (int mi = 0; mi < 4; ++mi)
#pragma unroll
      for (int r = 0; r < 4; ++r) {
        int rw = rbase + mi * 16 + r;
        tmp[mi][r] = fmaxf(fmaxf(red[0][rw], red[1][rw]), fmaxf(red[2][rw], red[3][rw]));
      }
    __syncthreads();
#pragma unroll
    for (int mi = 0; mi < 4; ++mi)
#pragma unroll
      for (int r = 0; r < 4; ++r) {
        float m = tmp[mi][r], s = 0.f;
#pragma unroll
        for (int ni = 0; ni < 4; ++ni) {
          float p = __expf(0.25f * (acc[mi][ni][r] - m));
          acc[mi][ni][r] = p;
          s += p;
        }
        s += __shfl_xor(s, 1);
        s += __shfl_xor(s, 2);
        s += __shfl_xor(s, 4);
        s += __shfl_xor(s, 8);
        tmp[mi][r] = s;
      }
    if (l15 == 0) {
#pragma unroll
      for (int mi = 0; mi < 4; ++mi)
#pragma unroll
        for (int r = 0; r < 4; ++r) red[wc][rbase + mi * 16 + r] = tmp[mi][r];
    }
    __syncthreads();
#pragma unroll
    for (int mi = 0; mi < 4; ++mi)
#pragma unroll
      for (int r = 0; r < 4; ++r) {
        int rw = rbase + mi * 16 + r;
        inv[mi][r] = __fdividef(1.0f, red[0][rw] + red[1][rw] + red[2][rw] + red[3][rw]);
      }
    __syncthreads();
  }
  // ---- P -> LDS (swizzled rows; block-local c in [0,128)) ----
#pragma unroll
  for (int mi = 0; mi < 4; ++mi)
#pragma unroll
    for (int ni = 0; ni < 4; ++ni) {
      int d = wc * 64 + ni * 16 + l15;
#pragma unroll
      for (int r = 0; r < 4; ++r) {
        int c = rbase + mi * 16 + r;
        bf16 p = (bf16)(acc1[mi][ni][r] * inv1[mi][r] - lam * acc2[mi][ni][r] * inv2[mi][r]);
        *(bf16*)(Pb + c * 512 + ((2 * d) ^ ((c & 7) << 4))) = p;
      }
    }
  asm volatile("s_waitcnt lgkmcnt(0)" ::: "memory");
  // ---- PV phase: pre[c][e] = sum_d P[c][d] * vT[e][d] ----
  const bf16* Bb = vT + (size_t)lz * E * E;
  f32x4 acc[4][4];
#pragma unroll
  for (int a = 0; a < 4; ++a)
#pragma unroll
    for (int b = 0; b < 4; ++b) acc[a][b] = z4;
  for (int k0 = 0; k0 < 256; k0 += 64) {
    __syncthreads();
#pragma unroll
    for (int i = 0; i < 4; ++i) {
      int rb = i * 64 + wv * 8;
      gload16(&Bb[(size_t)(rb + lrow) * E + k0 + kel], &Bs[rb][0]);
    }
    __syncthreads();
    __builtin_amdgcn_s_setprio(1);
#pragma unroll
    for (int kk = 0; kk < 2; ++kk) {
      int kb2 = (kk * 64 + (l4 << 4)) ^ ((lane & 7) << 4);
      bf16x8 af[4], bfr[4];
#pragma unroll
      for (int mi = 0; mi < 4; ++mi) {
        int c = wr * 64 + mi * 16 + l15;
        int kbP = (k0 * 2 + kk * 64 + (l4 << 4)) ^ ((c & 7) << 4);
        af[mi] = *(const bf16x8*)(Pb + c * 512 + kbP);
      }
#pragma unroll
      for (int ni = 0; ni < 4; ++ni)
        bfr[ni] = *(const bf16x8*)((const char*)Bs + (wc * 64 + ni * 16 + l15) * 128 + kb2);
#pragma unroll
      for (int mi = 0; mi < 4; ++mi)
#pragma unroll
        for (int ni = 0; ni < 4; ++ni)
          acc[mi][ni] = __builtin_amdgcn_mfma_f32_16x16x32_bf16(af[mi], bfr[ni],
                                                                acc[mi][ni], 0, 0, 0);
    }
    __builtin_amdgcn_s_setprio(0);
  }
  // ---- row-rmsnorm + residual epilogue (k_pv verbatim) ----
  float rowinv[4][4];
#pragma unroll
  for (int mi = 0; mi < 4; ++mi)
#pragma unroll
    for (int r = 0; r < 4; ++r) {
      float s = 0.f;
#pragma unroll
      for (int ni = 0; ni < 4; ++ni) {
        float v = acc[mi][ni][r];
        s += v * v;
      }
      s += __shfl_xor(s, 1);
      s += __shfl_xor(s, 2);
      s += __shfl_xor(s, 4);
      s += __shfl_xor(s, 8);
      rowinv[mi][r] = s;
    }
  __syncthreads();
  if (l15 == 0) {
#pragma unroll
    for (int mi = 0; mi < 4; ++mi)
#pragma unroll
      for (int r = 0; r < 4; ++r) red[wc][rbase + mi * 16 + r] = rowinv[mi][r];
  }
  __syncthreads();
#pragma unroll
  for (int mi = 0; mi < 4; ++mi)
#pragma unroll
    for (int r = 0; r < 4; ++r) {
      int rw = rbase + mi * 16 + r;
      float tot = red[0][rw] + red[1][rw] + red[2][rw] + red[3][rw];
      rowinv[mi][r] = oml * __fdividef(1.0f, sqrtf(tot) * 0.0625f + 1e-8f);
    }
  size_t bo = (size_t)lz * E * E;
  const float* xb = x + (size_t)(batchBase + lz) * E * E;
#pragma unroll
  for (int mi = 0; mi < 4; ++mi)
#pragma unroll
    for (int ni = 0; ni < 4; ++ni) {
      int col = wc * 64 + ni * 16 + l15;
      float ns = nscale[col];
      int row0 = mb + rbase + mi * 16;
      f32x4 xv = *(const f32x4*)&xb[(size_t)col * E + row0];
#pragma unroll
      for (int r = 0; r < 4; ++r) {
        size_t o = bo + (size_t)(row0 + r) * E + col;
        Y[o] = (bf16)(xv[r] + ns * acc[mi][ni][r] * rowinv[mi][r]);
      }
    }
}

// ---------------- fused column-RMS of Y + scale -> xn (bf16) ----------------------
__global__ __launch_bounds__(256) void k_ffnorm(const bf16* __restrict__ Y,
                                                const float* __restrict__ lnff,
                                                bf16* __restrict__ xn) {
  __shared__ float red[8][33];
  __shared__ float rl[32];
  int lz = blockIdx.y;
  int i0 = blockIdx.x << 5;
  int t = threadIdx.x, ic = t & 31, jg = t >> 5;
  size_t bo = (size_t)lz * E * E;
  float s = 0.f;
#pragma unroll 4
  for (int jj = 0; jj < 32; ++jj) {
    int j = jg + jj * 8;
    float v = (float)Y[bo + (size_t)j * E + i0 + ic];
    s += v * v;
  }
  red[jg][ic] = s;
  __syncthreads();
  if (jg == 0) {
    float tot = 0.f;
#pragma unroll
    for (int g2 = 0; g2 < 8; ++g2) tot += red[g2][ic];
    rl[ic] = __fdividef(1.0f, sqrtf(tot) * 0.0625f + 1e-8f);
  }
  __syncthreads();
  float rinv = rl[ic];
#pragma unroll 4
  for (int jj = 0; jj < 32; ++jj) {
    int j = jg + jj * 8;
    size_t o = bo + (size_t)j * E + i0 + ic;
    xn[o] = (bf16)(lnff[j] * (float)Y[o] * rinv);
  }
}

// ---------------- fused FFN (round-6 schedule: issue-early + vmcnt(2), 2 barriers) -
__global__ __launch_bounds__(1024) void k_ffn(const bf16* __restrict__ xn,
                                              const bf16* __restrict__ W1T,
                                              const bf16* __restrict__ W2T,
                                              const float* __restrict__ b1,
                                              const float* __restrict__ b2,
                                              const bf16* __restrict__ Y,
                                              int batchBase, float* __restrict__ out) {
  __shared__ __align__(128) char arena[131072];
  char* Hb = arena;               // 32 KB: H-chunk [64 c][256 e1], eb^(c&7) swizzle
  char* xnL = arena + 32768;      // 32 KB: xn tile as [4 ksub][64 c][64 k]
  char* S0 = arena + 65536;       // 32 KB staging dbuf
  char* S1 = arena + 98304;       // 32 KB
  int bid = blockIdx.x;
  int lz = bid >> 2;
  int c0 = (bid & 3) << 6;
  const bf16* xb = xn + (size_t)lz * E * E + (size_t)c0 * E;
  int t = threadIdx.x, lane = t & 63, wv = t >> 6;
  int lrow = lane >> 3;
  int kel = ((lane & 7) ^ lrow) << 3;
  int l15 = lane & 15, l4 = lane >> 4, l7 = lane & 7;
  int wr1 = wv >> 3, wc1 = wv & 7;   // ph1: 2(M=c64) x 8(N=e1-256)
  int wr2 = wv >> 1, wc2 = wv & 1;   // ph2: 8(M=e2-256) x 2(N=c64)

  float b1v[4][2];
#pragma unroll
  for (int ch = 0; ch < 4; ++ch)
#pragma unroll
    for (int ni = 0; ni < 2; ++ni)
      b1v[ch][ni] = b1[ch * 256 + wc1 * 32 + ni * 16 + l15];

#pragma unroll
  for (int j = 0; j < 2; ++j) {
    int lin = wv * 2 + j;
    int ksub = lin >> 3, rg = (lin & 7) * 8;
    gload16(&xb[(size_t)(rg + lrow) * E + ksub * 64 + kel], xnL + ksub * 8192 + rg * 128);
  }
#pragma unroll
  for (int i = 0; i < 2; ++i) {
    int rb = i * 128 + wv * 8;
    gload16(&W1T[(size_t)(rb + lrow) * 256 + kel], S0 + rb * 128);
  }

  f32x4 acc2[2][2];
  const f32x4 z4 = {0.f, 0.f, 0.f, 0.f};
  acc2[0][0] = z4; acc2[0][1] = z4; acc2[1][0] = z4; acc2[1][1] = z4;
  int cur = 0;

  for (int ch = 0; ch < 4; ++ch) {
    f32x4 acc1[2][2];
    acc1[0][0] = z4; acc1[0][1] = z4; acc1[1][0] = z4; acc1[1][1] = z4;
    for (int k = 0; k < 4; ++k) {
      char* Sn = cur ? S0 : S1;
      if (k < 3) {
#pragma unroll
        for (int i = 0; i < 2; ++i) {
          int rb = i * 128 + wv * 8;
          gload16(&W1T[(size_t)(ch * 256 + rb + lrow) * 256 + (k + 1) * 64 + kel], Sn + rb * 128);
        }
      } else {
#pragma unroll
        for (int i = 0; i < 2; ++i) {
          int rb = i * 128 + wv * 8;
          gload16(&W2T[(size_t)(rb + lrow) * 1024 + ch * 256 + kel], Sn + rb * 128);
        }
      }
      asm volatile("s_waitcnt vmcnt(2)" ::: "memory");
      __builtin_amdgcn_s_barrier();
      char* Sc = cur ? S1 : S0;
#pragma unroll
      for (int kk = 0; kk < 2; ++kk) {
        int kb = (kk * 64 + (l4 << 4)) ^ (l7 << 4);
        bf16x8 af[2], bfr[2];
#pragma unroll
        for (int mi = 0; mi < 2; ++mi)
          af[mi] = *(const bf16x8*)(xnL + k * 8192 + (wr1 * 32 + mi * 16 + l15) * 128 + kb);
#pragma unroll
        for (int ni = 0; ni < 2; ++ni)
          bfr[ni] = *(const bf16x8*)(Sc + (wc1 * 32 + ni * 16 + l15) * 128 + kb);
#pragma unroll
        for (int mi = 0; mi < 2; ++mi)
#pragma unroll
          for (int ni = 0; ni < 2; ++ni)
            acc1[mi][ni] = __builtin_amdgcn_mfma_f32_16x16x32_bf16(af[mi], bfr[ni],
                                                                   acc1[mi][ni], 0, 0, 0);
      }
      __builtin_amdgcn_s_barrier();
      cur ^= 1;
    }
#pragma unroll
    for (int mi = 0; mi < 2; ++mi)
#pragma unroll
      for (int ni = 0; ni < 2; ++ni) {
        int e1 = wc1 * 32 + ni * 16 + l15;
        float bN = b1v[ch][ni];
#pragma unroll
        for (int r = 0; r < 4; ++r) {
          int c = wr1 * 32 + mi * 16 + l4 * 4 + r;
          float u = acc1[mi][ni][r] + bN;
          float h = u * fsig(u);
          int bo2 = c * 512 + ((((e1 >> 3) ^ (c & 7)) << 4) | ((e1 & 7) * 2));
          *(bf16*)(Hb + bo2) = (bf16)h;
        }
      }
    asm volatile("s_waitcnt lgkmcnt(0)" ::: "memory");
    for (int k = 0; k < 4; ++k) {
      char* Sn = cur ? S0 : S1;
      bool isLast = (ch == 3) && (k == 3);
      if (k < 3) {
#pragma unroll
        for (int i = 0; i < 2; ++i) {
          int rb = i * 128 + wv * 8;
          gload16(&W2T[(size_t)(rb + lrow) * 1024 + ch * 256 + (k + 1) * 64 + kel], Sn + rb * 128);
        }
      } else if (ch < 3) {
#pragma unroll
        for (int i = 0; i < 2; ++i) {
          int rb = i * 128 + wv * 8;
          gload16(&W1T[(size_t)((ch + 1) * 256 + rb + lrow) * 256 + kel], Sn + rb * 128);
        }
      }
      if (isLast) asm volatile("s_waitcnt vmcnt(0)" ::: "memory");
      else        asm volatile("s_waitcnt vmcnt(2)" ::: "memory");
      __builtin_amdgcn_s_barrier();
      char* Sc = cur ? S1 : S0;
#pragma unroll
      for (int kk = 0; kk < 2; ++kk) {
        int kb = (kk * 64 + (l4 << 4)) ^ (l7 << 4);
        int kbH = (k * 128 + kk * 64 + (l4 << 4)) ^ (l7 << 4);
        bf16x8 af[2], bfr[2];
#pragma unroll
        for (int mi = 0; mi < 2; ++mi)
          af[mi] = *(const bf16x8*)(Sc + (wr2 * 32 + mi * 16 + l15) * 128 + kb);
#pragma unroll
        for (int ni = 0; ni < 2; ++ni)
          bfr[ni] = *(const bf16x8*)(Hb + (wc2 * 32 + ni * 16 + l15) * 512 + kbH);
#pragma unroll
        for (int mi = 0; mi < 2; ++mi)
#pragma unroll
          for (int ni = 0; ni < 2; ++ni)
            acc2[mi][ni] = __builtin_amdgcn_mfma_f32_16x16x32_bf16(af[mi], bfr[ni],
                                                                   acc2[mi][ni], 0, 0, 0);
      }
      __builtin_amdgcn_s_barrier();
      cur ^= 1;
    }
  }
  const bf16* Yb = Y + (size_t)lz * E * E;
  float* ob = out + (size_t)(batchBase + lz) * E * E;
#pragma unroll
  for (int mi = 0; mi < 2; ++mi) {
    int e2b = wr2 * 32 + mi * 16 + l4 * 4;
    f32x4 bv = *(const f32x4*)&b2[e2b];
#pragma unroll
    for (int ni = 0; ni < 2; ++ni) {
      int c = c0 + wc2 * 32 + ni * 16 + l15;
      bf16x4 yv = *(const bf16x4*)&Yb[(size_t)c * E + e2b];
#pragma unroll
      for (int r = 0; r < 4; ++r)
        ob[(size_t)(e2b + r) * E + c] = acc2[mi][ni][r] + bv[r] + (float)yv[r];
    }
  }
}

extern "C" void kernel_launch(void* const* d_in, const int* in_sizes, int n_in,
                              void* d_out, int out_size, void* d_ws, size_t ws_size,
                              hipStream_t stream) {
  const float* x = (const float*)d_in[0];
  const float* Wq = (const float*)d_in[1];
  const float* bq = (const float*)d_in[2];
  const float* Wk = (const float*)d_in[3];
  const float* bk = (const float*)d_in[4];
  const float* Wv = (const float*)d_in[5];
  const float* bv = (const float*)d_in[6];
  const float* lq1 = (const float*)d_in[7];
  const float* lk1 = (const float*)d_in[8];
  const float* lq2 = (const float*)d_in[9];
  const float* lk2 = (const float*)d_in[10];
  const float* lnattn = (const float*)d_in[11];
  const float* nscale = (const float*)d_in[12];
  const float* lnff = (const float*)d_in[13];
  const float* W1 = (const float*)d_in[14];
  const float* b1 = (const float*)d_in[15];
  const float* W2 = (const float*)d_in[16];
  const float* b2 = (const float*)d_in[17];
  float* out = (float*)d_out;

  char* ws = (char*)d_ws;
  size_t off = 0;
  auto alloc = [&](size_t bytes) {
    size_t o = off;
    off += (bytes + 255) & ~(size_t)255;
    return o;
  };
  size_t oWqT = alloc(512 * 256 * 2);
  size_t oWkT = alloc(512 * 256 * 2);
  size_t oWvT = alloc(256 * 256 * 2);
  size_t oW1T = alloc(1024 * 256 * 2);
  size_t oW2T = alloc(256 * 1024 * 2);
  size_t oLam = alloc(256);
  size_t weightEnd = off;

  const size_t szH = (size_t)E * E * 2;     // 128 KB bf16 matrix
  const size_t szQ = (size_t)E * 512 * 2;   // 256 KB bf16 [256][512]
  const size_t szRi = 1024;
  size_t perBatch = 4 * szH + 2 * szQ + szRi;
  size_t avail = ws_size > weightEnd ? ws_size - weightEnd : 0;
  int NB = (int)(avail / perBatch);
  if (NB > BTOT) NB = BTOT;
  if (NB < 1) NB = 1;

  size_t o = weightEnd;
  auto allocN = [&](size_t bytes) {
    size_t r = o;
    o += bytes * (size_t)NB;
    return r;
  };
  bf16* pA = (bf16*)(ws + allocN(szH));
  bf16* pTr = (bf16*)(ws + allocN(szH));
  bf16* pSe = (bf16*)(ws + allocN(szH));
  bf16* pVT = (bf16*)(ws + allocN(szH));
  size_t oQK = allocN(2 * szQ);             // q then k halves
  float* pRiA = (float*)(ws + allocN(szRi));

  bf16* pQ = (bf16*)(ws + oQK);
  bf16* pK = (bf16*)(ws + oQK + (size_t)NB * szQ);
  // aliases (consumed-before-written within each chunk, stream-ordered):
  bf16* pY = pA;
  bf16* pXn = pSe;

  bf16* pWqT = (bf16*)(ws + oWqT);
  bf16* pWkT = (bf16*)(ws + oWkT);
  bf16* pWvT = (bf16*)(ws + oWvT);
  bf16* pW1T = (bf16*)(ws + oW1T);
  bf16* pW2T = (bf16*)(ws + oW2T);
  float* pLam = (float*)(ws + oLam);

  const float LAMBDA_INIT = 0.8f - 0.6f * expf(-0.3f);
  const float OML = 1.0f - LAMBDA_INIT;

  // ---- prep (once) ----
  k_wT<<<dim3((256 / 32) * (512 / 32)), 256, 0, stream>>>(Wq, pWqT, 256, 512);
  k_wT<<<dim3((256 / 32) * (512 / 32)), 256, 0, stream>>>(Wk, pWkT, 256, 512);
  k_wT<<<dim3((256 / 32) * (256 / 32)), 256, 0, stream>>>(Wv, pWvT, 256, 256);
  k_wT<<<dim3((256 / 32) * (1024 / 32)), 256, 0, stream>>>(W1, pW1T, 256, 1024);
  k_wT<<<dim3((1024 / 32) * (256 / 32)), 256, 0, stream>>>(W2, pW2T, 1024, 256);
  k_lam<<<1, 256, 0, stream>>>(lq1, lk1, lq2, lk2, LAMBDA_INIT, pLam);

  for (int base = 0; base < BTOT; base += NB) {
    int cnt = BTOT - base < NB ? BTOT - base : NB;
    k_rmsA<<<dim3(cnt), 1024, 0, stream>>>(x, base, pRiA);
    k_prep<<<dim3(8, cnt), 256, 0, stream>>>(x, base, pRiA, lnattn, pA, pTr, pSe);
    // q & k projections merged into one dispatch (round-9 proven)
    gemm_qk<<<dim3(16 * cnt), 256, 0, stream>>>(pTr, pSe, pWqT, pWkT, pQ, pK, bq, bk, cnt);
    // vT[e][c] = WvT @ a_t^T + bv[e]
    gemm_bt<2><<<dim3(2 * 2 * cnt), 256, 0, stream>>>(pWvT, 256, 0, pA, 256, 65536,
        pVT, 256, 65536, 256, nullptr, bv, 2, 2, 2 * cnt);
    // fused attention: score + dual softmax + PV + row-rmsnorm + residual -> Y
    // (P stays in LDS; D buffer round-trip eliminated)   (overwrites pA via pY)
    k_attn<<<dim3(2 * cnt), 512, 0, stream>>>(pQ, pK, pVT, x, base, nscale, pLam,
                                              OML, pY, cnt);
    // xn = lnff[c] * Y * colrms(Y)   (overwrites pSe)
    k_ffnorm<<<dim3(8, cnt), 256, 0, stream>>>(pY, lnff, pXn);
    // fused FFN: out = W2T . silu(xn.W1T^T + b1) + b2 + Y   (h1 stays in LDS)
    k_ffn<<<dim3(4 * cnt), 1024, 0, stream>>>(pXn, pW1T, pW2T, b1, b2, pY, base, out);
  }
}